// Round 4
// baseline (2033.545 us; speedup 1.0000x reference)
//
#include <hip/hip_runtime.h>
#include <hip/hip_bf16.h>

// GCN1: 3-layer GraphConv x 4 graphs -> scalar grand mean.
// R4: XCD-sharded feature slicing for SpMM gathers. fp8 h stored as 8 slices
// of 40 fp8 (2 MB each); grid (8, NN/4) puts slice s on XCD s (blockid %8
// round-robin), so gathers hit a 2 MB working set inside one 4 MB L2.
// xs sliced x4 likewise. CSR build atomic-free (R3); MFMA bf16 GEMMs;
// layer-3 GEMM reduces relu(y) straight into a double accumulator.

#define NN 50000
#define EN 800000
#define NCH 64            // chunks per graph
#define CHE 12500         // edges per chunk (NCH*CHE == EN)
#define PBS 50016         // padded per-chunk histogram bytes (>= NN, %4==0)
#define SCB 49            // scan blocks per graph (49*1024 >= NN)

typedef unsigned int uint;
typedef unsigned short ushort;
typedef unsigned char uchar;
typedef short s8v __attribute__((ext_vector_type(8)));
typedef float f4v __attribute__((ext_vector_type(4)));
typedef float f2v __attribute__((ext_vector_type(2)));

__device__ inline ushort f2bf(float f) {
    uint u = __float_as_uint(f);
    uint r = (u + 0x7FFFu + ((u >> 16) & 1u)) >> 16;
    return (ushort)r;
}
__device__ inline uint pk2(float lo, float hi) {
    return (uint)f2bf(lo) | ((uint)f2bf(hi) << 16);
}
__device__ inline f4v mfma16(s8v a, s8v b, f4v c) {
    return __builtin_amdgcn_mfma_f32_16x16x32_bf16(a, b, c, 0, 0, 0);
}
__device__ inline uchar f2fp8(float f) {
    return (uchar)(__builtin_amdgcn_cvt_pk_fp8_f32(f, 0.f, 0, false) & 0xFF);
}

struct GP { const int* p[4]; };

// ---- CSR build (atomic-free) ----------------------------------------------

__global__ __launch_bounds__(256) void hist_kernel(GP src, GP dst,
                                                   uint* __restrict__ partS,
                                                   uint* __restrict__ partD) {
    int b = blockIdx.x, dir = blockIdx.y, g = blockIdx.z;
    const int* idx = dir ? dst.p[g] : src.p[g];
    __shared__ uint lh[PBS / 4];
    for (int i = threadIdx.x; i < PBS / 4; i += 256) lh[i] = 0;
    __syncthreads();
    int e0 = b * CHE;
    for (int e = e0 + threadIdx.x; e < e0 + CHE; e += 256) {
        uint n = (uint)idx[e];
        atomicAdd(&lh[n >> 2], 1u << (8 * (n & 3)));   // LDS atomic only
    }
    __syncthreads();
    uint* out = (dir ? partD : partS) + (size_t)(g * NCH + b) * (PBS / 4);
    for (int i = threadIdx.x; i < PBS / 4; i += 256) out[i] = lh[i];
}

__global__ __launch_bounds__(256) void reduce_kernel(const uchar* __restrict__ partS,
                                                     uchar* __restrict__ partD,
                                                     float* __restrict__ ns,
                                                     float* __restrict__ nd,
                                                     int* __restrict__ degd) {
    int idx = blockIdx.x * 256 + threadIdx.x;
    if (idx >= 4 * NN) return;
    int g = idx / NN, n = idx - g * NN;
    const uchar* ps = partS + (size_t)(g * NCH) * PBS + n;
    uint ss = 0;
    for (int b = 0; b < NCH; b++) ss += ps[(size_t)b * PBS];
    uchar* pd = partD + (size_t)(g * NCH) * PBS + n;
    uint run = 0;
    for (int b = 0; b < NCH; b++) {
        uint v = pd[(size_t)b * PBS];
        pd[(size_t)b * PBS] = (uchar)run;
        run += v;
    }
    ns[idx] = rsqrtf((float)max(ss, 1u));
    nd[idx] = rsqrtf((float)max(run, 1u));
    degd[idx] = (int)run;
}

__global__ __launch_bounds__(1024) void scan1_kernel(const int* __restrict__ degd,
                                                     int* __restrict__ rs_all,
                                                     int* __restrict__ bsum) {
    int j = blockIdx.x, g = blockIdx.y;
    int i = j * 1024 + threadIdx.x;
    int v = (i < NN) ? degd[g * NN + i] : 0;
    int lane = threadIdx.x & 63, w = threadIdx.x >> 6;
    int x = v;
    #pragma unroll
    for (int off = 1; off < 64; off <<= 1) {
        int t = __shfl_up(x, off, 64);
        if (lane >= off) x += t;
    }
    __shared__ int ws[17];
    if (lane == 63) ws[w] = x;
    __syncthreads();
    if (threadIdx.x == 0) {
        int run = 0;
        #pragma unroll
        for (int k = 0; k < 16; k++) { int t = ws[k]; ws[k] = run; run += t; }
        ws[16] = run;
    }
    __syncthreads();
    if (i < NN) rs_all[g * (NN + 1) + i] = ws[w] + x - v;
    if (threadIdx.x == 0) bsum[g * SCB + j] = ws[16];
}

__global__ void scan2_kernel(int* __restrict__ bsum, int* __restrict__ rs_all) {
    int g = threadIdx.x >> 6, lane = threadIdx.x & 63;
    int v = (lane < SCB) ? bsum[g * SCB + lane] : 0;
    int x = v;
    #pragma unroll
    for (int off = 1; off < 64; off <<= 1) {
        int t = __shfl_up(x, off, 64);
        if (lane >= off) x += t;
    }
    if (lane < SCB) bsum[g * SCB + lane] = x - v;   // exclusive
    if (lane == 63) rs_all[g * (NN + 1) + NN] = x;  // total (== EN)
}

__global__ __launch_bounds__(1024) void scan3_kernel(const int* __restrict__ bsum,
                                                     int* __restrict__ rs_all) {
    int j = blockIdx.x, g = blockIdx.y;
    int i = j * 1024 + threadIdx.x;
    int off = bsum[g * SCB + j];
    if (i < NN) rs_all[g * (NN + 1) + i] += off;
}

__global__ __launch_bounds__(256) void scatter_kernel(GP src, GP dst,
                                                      const int* __restrict__ rs_all,
                                                      const uchar* __restrict__ pf,
                                                      int* __restrict__ csr) {
    int b = blockIdx.x, g = blockIdx.y;
    __shared__ uint lc[PBS / 4];
    for (int i = threadIdx.x; i < PBS / 4; i += 256) lc[i] = 0;
    __syncthreads();
    const int* sp = src.p[g];
    const int* dp = dst.p[g];
    const int* rs = rs_all + g * (NN + 1);
    const uchar* pfb = pf + (size_t)(g * NCH + b) * PBS;
    int* csrg = csr + (size_t)g * EN;
    int e0 = b * CHE;
    for (int e = e0 + threadIdx.x; e < e0 + CHE; e += 256) {
        uint d = (uint)dp[e];
        int s = sp[e];
        uint sh = 8 * (d & 3);
        uint old = atomicAdd(&lc[d >> 2], 1u << sh);
        uint r = (old >> sh) & 0xFFu;
        csrg[rs[d] + (int)pfb[d] + (int)r] = s;
    }
}

// ---- weight transpose/pad to bf16: Wt[n][k], stride WS = K+8 ---------------

__global__ __launch_bounds__(256) void wtrans_kernel(const float* __restrict__ W,
                                                     ushort* __restrict__ Wt,
                                                     int Kreal, int WS) {
    int idx = blockIdx.x * 256 + threadIdx.x;
    if (idx >= 320 * WS) return;
    int n = idx / WS, k = idx - n * WS;
    float v = (n < 304 && k < Kreal) ? W[k * 304 + n] : 0.f;
    Wt[idx] = f2bf(v);
}

// ---- prescale: xs = fp8(x * ns), sliced [4][NN][8 dwords] ------------------

__global__ __launch_bounds__(256) void prescale_kernel(const float* __restrict__ x,
                                                       const float* __restrict__ ns,
                                                       uint* __restrict__ xs) {
    int idx = blockIdx.x * 256 + threadIdx.x;   // over NN*16 uint2 units
    if (idx >= NN * 16) return;
    int row = idx >> 4, j = idx & 15;
    int sl = j >> 2, pos = j & 3;
    float nv = ns[row];
    float4 v0 = ((const float4*)x)[idx * 2];
    float4 v1 = ((const float4*)x)[idx * 2 + 1];
    int p0 = 0, p1 = 0;
    p0 = __builtin_amdgcn_cvt_pk_fp8_f32(v0.x * nv, v0.y * nv, p0, false);
    p0 = __builtin_amdgcn_cvt_pk_fp8_f32(v0.z * nv, v0.w * nv, p0, true);
    p1 = __builtin_amdgcn_cvt_pk_fp8_f32(v1.x * nv, v1.y * nv, p1, false);
    p1 = __builtin_amdgcn_cvt_pk_fp8_f32(v1.z * nv, v1.w * nv, p1, true);
    ((uint2*)xs)[(size_t)sl * NN * 4 + row * 4 + pos] = make_uint2((uint)p0, (uint)p1);
}

// ---- SpMM (sliced): grid (slices, NN/4), 256 thr = 4 waves = 4 nodes -------

// xs: 4 slices x [NN][8 dwords] (32 fp8). m1 out: contiguous bf16 [NN][64 dw].
// Wave: 8 edge-groups x 8 lanes; butterfly reduce; lanes 0-7 write.
__global__ __launch_bounds__(256) void spmm128_kernel(const uint* __restrict__ xs,
                                                      const int* __restrict__ rs,
                                                      const int* __restrict__ csr,
                                                      const float* __restrict__ nd,
                                                      uint* __restrict__ out) {
    int wv = threadIdx.x >> 6, lane = threadIdx.x & 63;
    int node = blockIdx.y * 4 + wv;
    int sl = blockIdx.x;
    const uint* base = xs + (size_t)sl * NN * 8;
    int e0 = rs[node], e1 = rs[node + 1];
    int grp = lane >> 3, gl = lane & 7;
    float a0 = 0.f, a1 = 0.f, a2 = 0.f, a3 = 0.f;
    for (int e = e0 + grp; e < e1; e += 8) {
        int s = csr[e];
        uint d = base[(size_t)s * 8 + gl];
        f2v lo = __builtin_amdgcn_cvt_pk_f32_fp8(d, false);
        f2v hi = __builtin_amdgcn_cvt_pk_f32_fp8(d, true);
        a0 += lo[0]; a1 += lo[1]; a2 += hi[0]; a3 += hi[1];
    }
    #pragma unroll
    for (int off = 8; off < 64; off <<= 1) {
        a0 += __shfl_xor(a0, off, 64);
        a1 += __shfl_xor(a1, off, 64);
        a2 += __shfl_xor(a2, off, 64);
        a3 += __shfl_xor(a3, off, 64);
    }
    if (grp == 0) {
        float nv = nd[node];
        ((uint2*)out)[(size_t)node * 32 + sl * 8 + gl] =
            make_uint2(pk2(a0 * nv, a1 * nv), pk2(a2 * nv, a3 * nv));
    }
}

// hs: 8 slices x [NN][10 dwords] (40 fp8). out: contiguous bf16 [NN][160 dw].
// Wave: 6 edge-groups x 10 lanes (lanes 60-63 idle); 3-shfl reduce.
__global__ __launch_bounds__(256) void spmm320_kernel(const uint* __restrict__ hs,
                                                      const int* __restrict__ rs,
                                                      const int* __restrict__ csr,
                                                      const float* __restrict__ nd,
                                                      uint* __restrict__ out) {
    int wv = threadIdx.x >> 6, lane = threadIdx.x & 63;
    int node = blockIdx.y * 4 + wv;
    int sl = blockIdx.x;
    const uint* base = hs + (size_t)sl * NN * 10;
    int e0 = rs[node], e1 = rs[node + 1];
    int grp = lane / 10;             // 0..5 active, 6 idle
    int gl = lane - grp * 10;
    float a0 = 0.f, a1 = 0.f, a2 = 0.f, a3 = 0.f;
    int estart = (grp < 6) ? e0 + grp : e1;
    for (int e = estart; e < e1; e += 6) {
        int s = csr[e];
        uint d = base[(size_t)s * 10 + gl];
        f2v lo = __builtin_amdgcn_cvt_pk_f32_fp8(d, false);
        f2v hi = __builtin_amdgcn_cvt_pk_f32_fp8(d, true);
        a0 += lo[0]; a1 += lo[1]; a2 += hi[0]; a3 += hi[1];
    }
    // lanes 0-29 += lanes 30-59; then lanes 0-9 += (10-19)+(20-29)
    a0 += __shfl(a0, lane + 30, 64);
    a1 += __shfl(a1, lane + 30, 64);
    a2 += __shfl(a2, lane + 30, 64);
    a3 += __shfl(a3, lane + 30, 64);
    a0 = a0 + __shfl(a0, lane + 10, 64) + __shfl(a0, lane + 20, 64);
    a1 = a1 + __shfl(a1, lane + 10, 64) + __shfl(a1, lane + 20, 64);
    a2 = a2 + __shfl(a2, lane + 10, 64) + __shfl(a2, lane + 20, 64);
    a3 = a3 + __shfl(a3, lane + 10, 64) + __shfl(a3, lane + 20, 64);
    if (grp == 0) {
        float nv = nd[node];
        ((uint2*)out)[(size_t)node * 80 + sl * 10 + gl] =
            make_uint2(pk2(a0 * nv, a1 * nv), pk2(a2 * nv, a3 * nv));
    }
}

// ---- GEMM: C[M x 320] = A[M x K] @ Wt^T, epilogue relu(+bias) --------------
// !REDUCE writes fp8 into the 8-slice h layout. REDUCE sums into double.

template<int KSTEPS, bool REDUCE>
__global__ __launch_bounds__(256) void gemm_kernel(const ushort* __restrict__ A, int astride,
                                                   const ushort* __restrict__ Wt,
                                                   const float* __restrict__ bias,
                                                   const float* __restrict__ ns,
                                                   uchar* __restrict__ Hout,
                                                   double* __restrict__ accum,
                                                   int M) {
    constexpr int K = KSTEPS * 32;
    constexpr int WS = K + 8;   // pad: 2-way LDS conflicts only (free)
    __shared__ __align__(16) ushort wt[80 * WS];
    __shared__ float redbuf[4];
    int tid = threadIdx.x, lane = tid & 63, wv = tid >> 6;
    int nb = blockIdx.y * 80;
    int r0 = blockIdx.x * 128 + wv * 32;

    {   // stage 80 rows of Wt (16B vectors)
        const s8v* src = (const s8v*)(Wt + (size_t)nb * WS);
        s8v* dst = (s8v*)wt;
        for (int i = tid; i < 80 * WS / 8; i += 256) dst[i] = src[i];
    }
    __syncthreads();

    f4v acc[2][5];
    #pragma unroll
    for (int t = 0; t < 2; t++)
        #pragma unroll
        for (int j = 0; j < 5; j++) acc[t][j] = (f4v){0.f, 0.f, 0.f, 0.f};

    int m15 = lane & 15;
    int kq = (lane >> 4) * 8;
    int ar0 = min(r0 + m15, M - 1);
    int ar1 = min(r0 + 16 + m15, M - 1);
    const ushort* a0p = A + (size_t)ar0 * astride + kq;
    const ushort* a1p = A + (size_t)ar1 * astride + kq;
    const ushort* bb = wt + (size_t)m15 * WS + kq;

    #pragma unroll
    for (int ks = 0; ks < KSTEPS; ks++) {
        s8v af0 = *(const s8v*)(a0p + ks * 32);
        s8v af1 = *(const s8v*)(a1p + ks * 32);
        #pragma unroll
        for (int nt = 0; nt < 5; nt++) {
            s8v bf = *(const s8v*)(bb + nt * 16 * WS + ks * 32);
            acc[0][nt] = mfma16(af0, bf, acc[0][nt]);
            acc[1][nt] = mfma16(af1, bf, acc[1][nt]);
        }
    }

    int rq = (lane >> 4) * 4;   // C/D: col = lane&15, row = (lane>>4)*4 + reg
    if constexpr (!REDUCE) {
        float nsv[2][4];
        #pragma unroll
        for (int t = 0; t < 2; t++)
            #pragma unroll
            for (int r = 0; r < 4; r++) {
                int row = r0 + t * 16 + rq + r;
                nsv[t][r] = (row < M) ? ns[row] : 0.f;
            }
        #pragma unroll
        for (int nt = 0; nt < 5; nt++) {
            int col = nb + nt * 16 + m15;
            float bv = (col < 304) ? bias[col] : 0.f;
            int sl = col / 40, cw = col - sl * 40;
            uchar* hp = Hout + (size_t)sl * NN * 40 + cw;
            #pragma unroll
            for (int t = 0; t < 2; t++)
                #pragma unroll
                for (int r = 0; r < 4; r++) {
                    int row = r0 + t * 16 + rq + r;
                    if (row < M) {
                        float y = fmaxf(acc[t][nt][r] + bv, 0.f) * nsv[t][r];
                        hp[(size_t)row * 40] = f2fp8(y);
                    }
                }
        }
    } else {
        float s = 0.f;
        #pragma unroll
        for (int nt = 0; nt < 5; nt++) {
            int col = nb + nt * 16 + m15;
            float bv = (col < 304) ? bias[col] : 0.f;
            #pragma unroll
            for (int t = 0; t < 2; t++)
                #pragma unroll
                for (int r = 0; r < 4; r++) {
                    int row = r0 + t * 16 + rq + r;
                    if (row < M && col < 304) s += fmaxf(acc[t][nt][r] + bv, 0.f);
                }
        }
        #pragma unroll
        for (int off = 32; off; off >>= 1) s += __shfl_xor(s, off, 64);
        if (lane == 0) redbuf[wv] = s;
        __syncthreads();
        if (tid == 0) {
            double b = (double)redbuf[0] + redbuf[1] + redbuf[2] + redbuf[3];
            atomicAdd(accum, b);
        }
    }
}

__global__ void finalize_kernel(const double* __restrict__ accum, float* __restrict__ out) {
    out[0] = (float)(accum[0] / (double)(4.0 * NN * 304.0));
}

// ---- host ------------------------------------------------------------------

extern "C" void kernel_launch(void* const* d_in, const int* in_sizes, int n_in,
                              void* d_out, int out_size, void* d_ws, size_t ws_size,
                              hipStream_t stream) {
    char* w = (char*)d_ws;
    auto alloc = [&](size_t bytes) {
        char* p = w;
        w += (bytes + 255) & ~(size_t)255;
        return p;
    };
    double* accum  = (double*)alloc(256);
    int*    degd   = (int*)alloc((size_t)4 * NN * 4);
    int*    rs     = (int*)alloc((size_t)4 * (NN + 1) * 4);
    int*    bsum   = (int*)alloc((size_t)4 * SCB * 4);
    float*  nsrc   = (float*)alloc((size_t)4 * NN * 4);
    float*  ndst   = (float*)alloc((size_t)4 * NN * 4);
    int*    csr    = (int*)alloc((size_t)4 * EN * 4);
    ushort* wt1    = (ushort*)alloc((size_t)320 * 136 * 2);
    ushort* wt2    = (ushort*)alloc((size_t)320 * 328 * 2);
    ushort* wt3    = (ushort*)alloc((size_t)320 * 328 * 2);
    uint*   partS  = (uint*)alloc((size_t)4 * NCH * PBS);      // 12.8 MB
    uint*   partD  = (uint*)alloc((size_t)4 * NCH * PBS);      // 12.8 MB
    uint*   hbuf   = (uint*)alloc((size_t)NN * 80 * 4);        // fp8 8-slice N x 320
    uint*   mbuf   = (uint*)alloc((size_t)NN * 160 * 4);       // bf16 N x 320
    // partS/partD dead after scatter: alias layer-1 buffers onto them.
    uint*   xs     = partS;   // fp8 4-slice N x 128: 6.4 MB  <= 12.8 MB
    uint*   m1     = partD;   // bf16 N x 128: 12.8 MB <= 12.8 MB

    hipMemsetAsync(accum, 0, 256, stream);

    wtrans_kernel<<<(320 * 136 + 255) / 256, 256, 0, stream>>>((const float*)d_in[12], wt1, 128, 136);
    wtrans_kernel<<<(320 * 328 + 255) / 256, 256, 0, stream>>>((const float*)d_in[14], wt2, 304, 328);
    wtrans_kernel<<<(320 * 328 + 255) / 256, 256, 0, stream>>>((const float*)d_in[16], wt3, 304, 328);

    GP S, D;
    for (int g = 0; g < 4; g++) {
        S.p[g] = (const int*)d_in[1 + 3 * g];
        D.p[g] = (const int*)d_in[2 + 3 * g];
    }
    hist_kernel<<<dim3(NCH, 2, 4), 256, 0, stream>>>(S, D, partS, partD);
    reduce_kernel<<<(4 * NN + 255) / 256, 256, 0, stream>>>((const uchar*)partS, (uchar*)partD,
                                                            nsrc, ndst, degd);
    scan1_kernel<<<dim3(SCB, 4), 1024, 0, stream>>>(degd, rs, bsum);
    scan2_kernel<<<1, 256, 0, stream>>>(bsum, rs);
    scan3_kernel<<<dim3(SCB, 4), 1024, 0, stream>>>(bsum, rs);
    scatter_kernel<<<dim3(NCH, 4), 256, 0, stream>>>(S, D, rs, (const uchar*)partD, csr);

    const float* b1 = (const float*)d_in[13];
    const float* b2 = (const float*)d_in[15];
    const float* b3 = (const float*)d_in[17];
    dim3 ggrid((NN + 127) / 128, 4);

    for (int g = 0; g < 4; g++) {
        const float* xin = (const float*)d_in[3 * g];
        const float* nsg = nsrc + g * NN;
        const float* ndg = ndst + g * NN;
        const int* rsg = rs + g * (NN + 1);
        const int* csrg = csr + (size_t)g * EN;

        prescale_kernel<<<(NN * 16 + 255) / 256, 256, 0, stream>>>(xin, nsg, xs);
        spmm128_kernel<<<dim3(4, NN / 4), 256, 0, stream>>>(xs, rsg, csrg, ndg, m1);
        gemm_kernel<4, false><<<ggrid, 256, 0, stream>>>((const ushort*)m1, 128, wt1, b1, nsg,
                                                         (uchar*)hbuf, nullptr, NN);
        spmm320_kernel<<<dim3(8, NN / 4), 256, 0, stream>>>(hbuf, rsg, csrg, ndg, mbuf);
        gemm_kernel<10, false><<<ggrid, 256, 0, stream>>>((const ushort*)mbuf, 320, wt2, b2, nsg,
                                                          (uchar*)hbuf, nullptr, NN);
        spmm320_kernel<<<dim3(8, NN / 4), 256, 0, stream>>>(hbuf, rsg, csrg, ndg, mbuf);
        gemm_kernel<10, true><<<ggrid, 256, 0, stream>>>((const ushort*)mbuf, 320, wt3, b3, nullptr,
                                                         nullptr, accum, NN);
    }
    finalize_kernel<<<1, 1, 0, stream>>>(accum, (float*)d_out);
}

// Round 5
// 1611.014 us; speedup vs baseline: 1.2623x; 1.2623x over previous
//
#include <hip/hip_runtime.h>
#include <hip/hip_bf16.h>

// GCN1: 3-layer GraphConv x 4 graphs -> scalar grand mean.
// R5: SpMM = XCD-sliced fp8 layout (R4) but lane-GROUP-owns-NODE: each group
// of 10 (or 8) lanes walks one node's edge list serially, accumulating its
// feature slice in registers -> no cross-group shuffles, 6 (8) independent
// load chains per wave, unroll-2 for MLP. csr stored as u16 (ids < 65536)
// halving the per-slice csr refetch. CSR build atomic-free (R3); MFMA bf16
// GEMMs; layer-3 GEMM reduces relu(y) straight into a double accumulator.

#define NN 50000
#define EN 800000
#define NCH 64            // chunks per graph
#define CHE 12500         // edges per chunk (NCH*CHE == EN)
#define PBS 50016         // padded per-chunk histogram bytes (>= NN, %4==0)
#define SCB 49            // scan blocks per graph (49*1024 >= NN)

typedef unsigned int uint;
typedef unsigned short ushort;
typedef unsigned char uchar;
typedef short s8v __attribute__((ext_vector_type(8)));
typedef float f4v __attribute__((ext_vector_type(4)));
typedef float f2v __attribute__((ext_vector_type(2)));

__device__ inline ushort f2bf(float f) {
    uint u = __float_as_uint(f);
    uint r = (u + 0x7FFFu + ((u >> 16) & 1u)) >> 16;
    return (ushort)r;
}
__device__ inline uint pk2(float lo, float hi) {
    return (uint)f2bf(lo) | ((uint)f2bf(hi) << 16);
}
__device__ inline f4v mfma16(s8v a, s8v b, f4v c) {
    return __builtin_amdgcn_mfma_f32_16x16x32_bf16(a, b, c, 0, 0, 0);
}
__device__ inline uchar f2fp8(float f) {
    return (uchar)(__builtin_amdgcn_cvt_pk_fp8_f32(f, 0.f, 0, false) & 0xFF);
}

struct GP { const int* p[4]; };

// ---- CSR build (atomic-free) ----------------------------------------------

__global__ __launch_bounds__(256) void hist_kernel(GP src, GP dst,
                                                   uint* __restrict__ partS,
                                                   uint* __restrict__ partD) {
    int b = blockIdx.x, dir = blockIdx.y, g = blockIdx.z;
    const int* idx = dir ? dst.p[g] : src.p[g];
    __shared__ uint lh[PBS / 4];
    for (int i = threadIdx.x; i < PBS / 4; i += 256) lh[i] = 0;
    __syncthreads();
    int e0 = b * CHE;
    for (int e = e0 + threadIdx.x; e < e0 + CHE; e += 256) {
        uint n = (uint)idx[e];
        atomicAdd(&lh[n >> 2], 1u << (8 * (n & 3)));   // LDS atomic only
    }
    __syncthreads();
    uint* out = (dir ? partD : partS) + (size_t)(g * NCH + b) * (PBS / 4);
    for (int i = threadIdx.x; i < PBS / 4; i += 256) out[i] = lh[i];
}

__global__ __launch_bounds__(256) void reduce_kernel(const uchar* __restrict__ partS,
                                                     uchar* __restrict__ partD,
                                                     float* __restrict__ ns,
                                                     float* __restrict__ nd,
                                                     int* __restrict__ degd) {
    int idx = blockIdx.x * 256 + threadIdx.x;
    if (idx >= 4 * NN) return;
    int g = idx / NN, n = idx - g * NN;
    const uchar* ps = partS + (size_t)(g * NCH) * PBS + n;
    uint ss = 0;
    for (int b = 0; b < NCH; b++) ss += ps[(size_t)b * PBS];
    uchar* pd = partD + (size_t)(g * NCH) * PBS + n;
    uint run = 0;
    for (int b = 0; b < NCH; b++) {
        uint v = pd[(size_t)b * PBS];
        pd[(size_t)b * PBS] = (uchar)run;
        run += v;
    }
    ns[idx] = rsqrtf((float)max(ss, 1u));
    nd[idx] = rsqrtf((float)max(run, 1u));
    degd[idx] = (int)run;
}

__global__ __launch_bounds__(1024) void scan1_kernel(const int* __restrict__ degd,
                                                     int* __restrict__ rs_all,
                                                     int* __restrict__ bsum) {
    int j = blockIdx.x, g = blockIdx.y;
    int i = j * 1024 + threadIdx.x;
    int v = (i < NN) ? degd[g * NN + i] : 0;
    int lane = threadIdx.x & 63, w = threadIdx.x >> 6;
    int x = v;
    #pragma unroll
    for (int off = 1; off < 64; off <<= 1) {
        int t = __shfl_up(x, off, 64);
        if (lane >= off) x += t;
    }
    __shared__ int ws[17];
    if (lane == 63) ws[w] = x;
    __syncthreads();
    if (threadIdx.x == 0) {
        int run = 0;
        #pragma unroll
        for (int k = 0; k < 16; k++) { int t = ws[k]; ws[k] = run; run += t; }
        ws[16] = run;
    }
    __syncthreads();
    if (i < NN) rs_all[g * (NN + 1) + i] = ws[w] + x - v;
    if (threadIdx.x == 0) bsum[g * SCB + j] = ws[16];
}

__global__ void scan2_kernel(int* __restrict__ bsum, int* __restrict__ rs_all) {
    int g = threadIdx.x >> 6, lane = threadIdx.x & 63;
    int v = (lane < SCB) ? bsum[g * SCB + lane] : 0;
    int x = v;
    #pragma unroll
    for (int off = 1; off < 64; off <<= 1) {
        int t = __shfl_up(x, off, 64);
        if (lane >= off) x += t;
    }
    if (lane < SCB) bsum[g * SCB + lane] = x - v;   // exclusive
    if (lane == 63) rs_all[g * (NN + 1) + NN] = x;  // total (== EN)
}

__global__ __launch_bounds__(1024) void scan3_kernel(const int* __restrict__ bsum,
                                                     int* __restrict__ rs_all) {
    int j = blockIdx.x, g = blockIdx.y;
    int i = j * 1024 + threadIdx.x;
    int off = bsum[g * SCB + j];
    if (i < NN) rs_all[g * (NN + 1) + i] += off;
}

__global__ __launch_bounds__(256) void scatter_kernel(GP src, GP dst,
                                                      const int* __restrict__ rs_all,
                                                      const uchar* __restrict__ pf,
                                                      ushort* __restrict__ csr) {
    int b = blockIdx.x, g = blockIdx.y;
    __shared__ uint lc[PBS / 4];
    for (int i = threadIdx.x; i < PBS / 4; i += 256) lc[i] = 0;
    __syncthreads();
    const int* sp = src.p[g];
    const int* dp = dst.p[g];
    const int* rs = rs_all + g * (NN + 1);
    const uchar* pfb = pf + (size_t)(g * NCH + b) * PBS;
    ushort* csrg = csr + (size_t)g * EN;
    int e0 = b * CHE;
    for (int e = e0 + threadIdx.x; e < e0 + CHE; e += 256) {
        uint d = (uint)dp[e];
        int s = sp[e];
        uint sh = 8 * (d & 3);
        uint old = atomicAdd(&lc[d >> 2], 1u << sh);
        uint r = (old >> sh) & 0xFFu;
        csrg[rs[d] + (int)pfb[d] + (int)r] = (ushort)s;
    }
}

// ---- weight transpose/pad to bf16: Wt[n][k], stride WS = K+8 ---------------

__global__ __launch_bounds__(256) void wtrans_kernel(const float* __restrict__ W,
                                                     ushort* __restrict__ Wt,
                                                     int Kreal, int WS) {
    int idx = blockIdx.x * 256 + threadIdx.x;
    if (idx >= 320 * WS) return;
    int n = idx / WS, k = idx - n * WS;
    float v = (n < 304 && k < Kreal) ? W[k * 304 + n] : 0.f;
    Wt[idx] = f2bf(v);
}

// ---- prescale: xs = fp8(x * ns), sliced [4][NN][8 dwords] ------------------

__global__ __launch_bounds__(256) void prescale_kernel(const float* __restrict__ x,
                                                       const float* __restrict__ ns,
                                                       uint* __restrict__ xs) {
    int idx = blockIdx.x * 256 + threadIdx.x;   // over NN*16 uint2 units
    if (idx >= NN * 16) return;
    int row = idx >> 4, j = idx & 15;
    int sl = j >> 2, pos = j & 3;
    float nv = ns[row];
    float4 v0 = ((const float4*)x)[idx * 2];
    float4 v1 = ((const float4*)x)[idx * 2 + 1];
    int p0 = 0, p1 = 0;
    p0 = __builtin_amdgcn_cvt_pk_fp8_f32(v0.x * nv, v0.y * nv, p0, false);
    p0 = __builtin_amdgcn_cvt_pk_fp8_f32(v0.z * nv, v0.w * nv, p0, true);
    p1 = __builtin_amdgcn_cvt_pk_fp8_f32(v1.x * nv, v1.y * nv, p1, false);
    p1 = __builtin_amdgcn_cvt_pk_fp8_f32(v1.z * nv, v1.w * nv, p1, true);
    ((uint2*)xs)[(size_t)sl * NN * 4 + row * 4 + pos] = make_uint2((uint)p0, (uint)p1);
}

// ---- SpMM (sliced, group-owns-node): no cross-lane reduction ---------------

// xs: 4 slices x [NN][8 dw]. Wave = 8 groups x 8 lanes; group g owns node.
// m1 out: contiguous bf16 [NN][64 dw]. Grid (4, ceil(NN/32)).
__global__ __launch_bounds__(256) void spmm128_kernel(const uint* __restrict__ xs,
                                                      const int* __restrict__ rs,
                                                      const ushort* __restrict__ csr,
                                                      const float* __restrict__ nd,
                                                      uint* __restrict__ out) {
    int wv = threadIdx.x >> 6, lane = threadIdx.x & 63;
    int grp = lane >> 3, gl = lane & 7;
    int node = blockIdx.y * 32 + wv * 8 + grp;
    int sl = blockIdx.x;
    const uint* base = xs + (size_t)sl * NN * 8;
    bool ok = node < NN;
    int e0 = ok ? rs[node] : 0, e1 = ok ? rs[node + 1] : 0;
    float a0 = 0.f, a1 = 0.f, a2 = 0.f, a3 = 0.f;
    for (int e = e0; e < e1; e += 2) {
        int s0 = csr[e];
        bool v2 = (e + 1 < e1);
        int s1 = csr[v2 ? e + 1 : e];
        uint d0 = base[(size_t)s0 * 8 + gl];
        uint d1 = base[(size_t)s1 * 8 + gl];
        f2v lo0 = __builtin_amdgcn_cvt_pk_f32_fp8(d0, false);
        f2v hi0 = __builtin_amdgcn_cvt_pk_f32_fp8(d0, true);
        a0 += lo0[0]; a1 += lo0[1]; a2 += hi0[0]; a3 += hi0[1];
        if (v2) {
            f2v lo1 = __builtin_amdgcn_cvt_pk_f32_fp8(d1, false);
            f2v hi1 = __builtin_amdgcn_cvt_pk_f32_fp8(d1, true);
            a0 += lo1[0]; a1 += lo1[1]; a2 += hi1[0]; a3 += hi1[1];
        }
    }
    if (ok) {
        float nv = nd[node];
        ((uint2*)out)[(size_t)node * 32 + sl * 8 + gl] =
            make_uint2(pk2(a0 * nv, a1 * nv), pk2(a2 * nv, a3 * nv));
    }
}

// hs: 8 slices x [NN][10 dw]. Wave = 6 groups x 10 lanes (lanes 60-63 idle).
// out: contiguous bf16 [NN][160 dw]. Grid (8, ceil(NN/24)).
__global__ __launch_bounds__(256) void spmm320_kernel(const uint* __restrict__ hs,
                                                      const int* __restrict__ rs,
                                                      const ushort* __restrict__ csr,
                                                      const float* __restrict__ nd,
                                                      uint* __restrict__ out) {
    int wv = threadIdx.x >> 6, lane = threadIdx.x & 63;
    int grp = lane / 10;             // 0..5 active, 6 idle
    int gl = lane - grp * 10;
    int node = blockIdx.y * 24 + wv * 6 + grp;
    int sl = blockIdx.x;
    const uint* base = hs + (size_t)sl * NN * 10;
    bool ok = (grp < 6) && (node < NN);
    int e0 = ok ? rs[node] : 0, e1 = ok ? rs[node + 1] : 0;
    float a0 = 0.f, a1 = 0.f, a2 = 0.f, a3 = 0.f;
    for (int e = e0; e < e1; e += 2) {
        int s0 = csr[e];
        bool v2 = (e + 1 < e1);
        int s1 = csr[v2 ? e + 1 : e];
        uint d0 = base[(size_t)s0 * 10 + gl];
        uint d1 = base[(size_t)s1 * 10 + gl];
        f2v lo0 = __builtin_amdgcn_cvt_pk_f32_fp8(d0, false);
        f2v hi0 = __builtin_amdgcn_cvt_pk_f32_fp8(d0, true);
        a0 += lo0[0]; a1 += lo0[1]; a2 += hi0[0]; a3 += hi0[1];
        if (v2) {
            f2v lo1 = __builtin_amdgcn_cvt_pk_f32_fp8(d1, false);
            f2v hi1 = __builtin_amdgcn_cvt_pk_f32_fp8(d1, true);
            a0 += lo1[0]; a1 += lo1[1]; a2 += hi1[0]; a3 += hi1[1];
        }
    }
    if (ok) {
        float nv = nd[node];
        ((uint2*)out)[(size_t)node * 80 + sl * 10 + gl] =
            make_uint2(pk2(a0 * nv, a1 * nv), pk2(a2 * nv, a3 * nv));
    }
}

// ---- GEMM: C[M x 320] = A[M x K] @ Wt^T, epilogue relu(+bias) --------------
// !REDUCE writes fp8 into the 8-slice h layout. REDUCE sums into double.

template<int KSTEPS, bool REDUCE>
__global__ __launch_bounds__(256) void gemm_kernel(const ushort* __restrict__ A, int astride,
                                                   const ushort* __restrict__ Wt,
                                                   const float* __restrict__ bias,
                                                   const float* __restrict__ ns,
                                                   uchar* __restrict__ Hout,
                                                   double* __restrict__ accum,
                                                   int M) {
    constexpr int K = KSTEPS * 32;
    constexpr int WS = K + 8;   // pad: 2-way LDS conflicts only (free)
    __shared__ __align__(16) ushort wt[80 * WS];
    __shared__ float redbuf[4];
    int tid = threadIdx.x, lane = tid & 63, wv = tid >> 6;
    int nb = blockIdx.y * 80;
    int r0 = blockIdx.x * 128 + wv * 32;

    {   // stage 80 rows of Wt (16B vectors)
        const s8v* src = (const s8v*)(Wt + (size_t)nb * WS);
        s8v* dst = (s8v*)wt;
        for (int i = tid; i < 80 * WS / 8; i += 256) dst[i] = src[i];
    }
    __syncthreads();

    f4v acc[2][5];
    #pragma unroll
    for (int t = 0; t < 2; t++)
        #pragma unroll
        for (int j = 0; j < 5; j++) acc[t][j] = (f4v){0.f, 0.f, 0.f, 0.f};

    int m15 = lane & 15;
    int kq = (lane >> 4) * 8;
    int ar0 = min(r0 + m15, M - 1);
    int ar1 = min(r0 + 16 + m15, M - 1);
    const ushort* a0p = A + (size_t)ar0 * astride + kq;
    const ushort* a1p = A + (size_t)ar1 * astride + kq;
    const ushort* bb = wt + (size_t)m15 * WS + kq;

    #pragma unroll
    for (int ks = 0; ks < KSTEPS; ks++) {
        s8v af0 = *(const s8v*)(a0p + ks * 32);
        s8v af1 = *(const s8v*)(a1p + ks * 32);
        #pragma unroll
        for (int nt = 0; nt < 5; nt++) {
            s8v bf = *(const s8v*)(bb + nt * 16 * WS + ks * 32);
            acc[0][nt] = mfma16(af0, bf, acc[0][nt]);
            acc[1][nt] = mfma16(af1, bf, acc[1][nt]);
        }
    }

    int rq = (lane >> 4) * 4;   // C/D: col = lane&15, row = (lane>>4)*4 + reg
    if constexpr (!REDUCE) {
        float nsv[2][4];
        #pragma unroll
        for (int t = 0; t < 2; t++)
            #pragma unroll
            for (int r = 0; r < 4; r++) {
                int row = r0 + t * 16 + rq + r;
                nsv[t][r] = (row < M) ? ns[row] : 0.f;
            }
        #pragma unroll
        for (int nt = 0; nt < 5; nt++) {
            int col = nb + nt * 16 + m15;
            float bv = (col < 304) ? bias[col] : 0.f;
            int sl = col / 40, cw = col - sl * 40;
            uchar* hp = Hout + (size_t)sl * NN * 40 + cw;
            #pragma unroll
            for (int t = 0; t < 2; t++)
                #pragma unroll
                for (int r = 0; r < 4; r++) {
                    int row = r0 + t * 16 + rq + r;
                    if (row < M) {
                        float y = fmaxf(acc[t][nt][r] + bv, 0.f) * nsv[t][r];
                        hp[(size_t)row * 40] = f2fp8(y);
                    }
                }
        }
    } else {
        float s = 0.f;
        #pragma unroll
        for (int nt = 0; nt < 5; nt++) {
            int col = nb + nt * 16 + m15;
            float bv = (col < 304) ? bias[col] : 0.f;
            #pragma unroll
            for (int t = 0; t < 2; t++)
                #pragma unroll
                for (int r = 0; r < 4; r++) {
                    int row = r0 + t * 16 + rq + r;
                    if (row < M && col < 304) s += fmaxf(acc[t][nt][r] + bv, 0.f);
                }
        }
        #pragma unroll
        for (int off = 32; off; off >>= 1) s += __shfl_xor(s, off, 64);
        if (lane == 0) redbuf[wv] = s;
        __syncthreads();
        if (tid == 0) {
            double b = (double)redbuf[0] + redbuf[1] + redbuf[2] + redbuf[3];
            atomicAdd(accum, b);
        }
    }
}

__global__ void finalize_kernel(const double* __restrict__ accum, float* __restrict__ out) {
    out[0] = (float)(accum[0] / (double)(4.0 * NN * 304.0));
}

// ---- host ------------------------------------------------------------------

extern "C" void kernel_launch(void* const* d_in, const int* in_sizes, int n_in,
                              void* d_out, int out_size, void* d_ws, size_t ws_size,
                              hipStream_t stream) {
    char* w = (char*)d_ws;
    auto alloc = [&](size_t bytes) {
        char* p = w;
        w += (bytes + 255) & ~(size_t)255;
        return p;
    };
    double* accum  = (double*)alloc(256);
    int*    degd   = (int*)alloc((size_t)4 * NN * 4);
    int*    rs     = (int*)alloc((size_t)4 * (NN + 1) * 4);
    int*    bsum   = (int*)alloc((size_t)4 * SCB * 4);
    float*  nsrc   = (float*)alloc((size_t)4 * NN * 4);
    float*  ndst   = (float*)alloc((size_t)4 * NN * 4);
    ushort* csr    = (ushort*)alloc((size_t)4 * EN * 2);       // u16 src ids
    ushort* wt1    = (ushort*)alloc((size_t)320 * 136 * 2);
    ushort* wt2    = (ushort*)alloc((size_t)320 * 328 * 2);
    ushort* wt3    = (ushort*)alloc((size_t)320 * 328 * 2);
    uint*   partS  = (uint*)alloc((size_t)4 * NCH * PBS);      // 12.8 MB
    uint*   partD  = (uint*)alloc((size_t)4 * NCH * PBS);      // 12.8 MB
    uint*   hbuf   = (uint*)alloc((size_t)NN * 80 * 4);        // fp8 8-slice N x 320
    uint*   mbuf   = (uint*)alloc((size_t)NN * 160 * 4);       // bf16 N x 320
    // partS/partD dead after scatter: alias layer-1 buffers onto them.
    uint*   xs     = partS;   // fp8 4-slice N x 128: 6.4 MB  <= 12.8 MB
    uint*   m1     = partD;   // bf16 N x 128: 12.8 MB <= 12.8 MB

    hipMemsetAsync(accum, 0, 256, stream);

    wtrans_kernel<<<(320 * 136 + 255) / 256, 256, 0, stream>>>((const float*)d_in[12], wt1, 128, 136);
    wtrans_kernel<<<(320 * 328 + 255) / 256, 256, 0, stream>>>((const float*)d_in[14], wt2, 304, 328);
    wtrans_kernel<<<(320 * 328 + 255) / 256, 256, 0, stream>>>((const float*)d_in[16], wt3, 304, 328);

    GP S, D;
    for (int g = 0; g < 4; g++) {
        S.p[g] = (const int*)d_in[1 + 3 * g];
        D.p[g] = (const int*)d_in[2 + 3 * g];
    }
    hist_kernel<<<dim3(NCH, 2, 4), 256, 0, stream>>>(S, D, partS, partD);
    reduce_kernel<<<(4 * NN + 255) / 256, 256, 0, stream>>>((const uchar*)partS, (uchar*)partD,
                                                            nsrc, ndst, degd);
    scan1_kernel<<<dim3(SCB, 4), 1024, 0, stream>>>(degd, rs, bsum);
    scan2_kernel<<<1, 256, 0, stream>>>(bsum, rs);
    scan3_kernel<<<dim3(SCB, 4), 1024, 0, stream>>>(bsum, rs);
    scatter_kernel<<<dim3(NCH, 4), 256, 0, stream>>>(S, D, rs, (const uchar*)partD, csr);

    const float* b1 = (const float*)d_in[13];
    const float* b2 = (const float*)d_in[15];
    const float* b3 = (const float*)d_in[17];
    dim3 ggrid((NN + 127) / 128, 4);

    for (int g = 0; g < 4; g++) {
        const float* xin = (const float*)d_in[3 * g];
        const float* nsg = nsrc + g * NN;
        const float* ndg = ndst + g * NN;
        const int* rsg = rs + g * (NN + 1);
        const ushort* csrg = csr + (size_t)g * EN;

        prescale_kernel<<<(NN * 16 + 255) / 256, 256, 0, stream>>>(xin, nsg, xs);
        spmm128_kernel<<<dim3(4, (NN + 31) / 32), 256, 0, stream>>>(xs, rsg, csrg, ndg, m1);
        gemm_kernel<4, false><<<ggrid, 256, 0, stream>>>((const ushort*)m1, 128, wt1, b1, nsg,
                                                         (uchar*)hbuf, nullptr, NN);
        spmm320_kernel<<<dim3(8, (NN + 23) / 24), 256, 0, stream>>>(hbuf, rsg, csrg, ndg, mbuf);
        gemm_kernel<10, false><<<ggrid, 256, 0, stream>>>((const ushort*)mbuf, 320, wt2, b2, nsg,
                                                          (uchar*)hbuf, nullptr, NN);
        spmm320_kernel<<<dim3(8, (NN + 23) / 24), 256, 0, stream>>>(hbuf, rsg, csrg, ndg, mbuf);
        gemm_kernel<10, true><<<ggrid, 256, 0, stream>>>((const ushort*)mbuf, 320, wt3, b3, nullptr,
                                                         nullptr, accum, NN);
    }
    finalize_kernel<<<1, 1, 0, stream>>>(accum, (float*)d_out);
}

// Round 6
// 1590.236 us; speedup vs baseline: 1.2788x; 1.0131x over previous
//
#include <hip/hip_runtime.h>
#include <hip/hip_bf16.h>

// GCN1: 3-layer GraphConv x 4 graphs -> scalar grand mean.
// R6: SpMM = XCD-sliced fp8 gathers (R4/R5, group-owns-node) + degree-sorted
// node permutation (counting sort by in-degree -> waves get equal-degree
// nodes, no divergent-loop waste) + unroll-4 gather loop (8 loads in flight).
// csr u16; CSR build atomic-free (R3); MFMA bf16 GEMMs; layer-3 GEMM reduces
// relu(y) straight into a double accumulator.

#define NN 50000
#define EN 800000
#define NCH 64            // chunks per graph
#define CHE 12500         // edges per chunk (NCH*CHE == EN)
#define PBS 50016         // padded per-chunk histogram bytes (>= NN, %4==0)
#define SCB 49            // scan blocks per graph (49*1024 >= NN)

typedef unsigned int uint;
typedef unsigned short ushort;
typedef unsigned char uchar;
typedef short s8v __attribute__((ext_vector_type(8)));
typedef float f4v __attribute__((ext_vector_type(4)));
typedef float f2v __attribute__((ext_vector_type(2)));

__device__ inline ushort f2bf(float f) {
    uint u = __float_as_uint(f);
    uint r = (u + 0x7FFFu + ((u >> 16) & 1u)) >> 16;
    return (ushort)r;
}
__device__ inline uint pk2(float lo, float hi) {
    return (uint)f2bf(lo) | ((uint)f2bf(hi) << 16);
}
__device__ inline f4v mfma16(s8v a, s8v b, f4v c) {
    return __builtin_amdgcn_mfma_f32_16x16x32_bf16(a, b, c, 0, 0, 0);
}
__device__ inline uchar f2fp8(float f) {
    return (uchar)(__builtin_amdgcn_cvt_pk_fp8_f32(f, 0.f, 0, false) & 0xFF);
}

struct GP { const int* p[4]; };

// ---- CSR build (atomic-free) ----------------------------------------------

__global__ __launch_bounds__(256) void hist_kernel(GP src, GP dst,
                                                   uint* __restrict__ partS,
                                                   uint* __restrict__ partD) {
    int b = blockIdx.x, dir = blockIdx.y, g = blockIdx.z;
    const int* idx = dir ? dst.p[g] : src.p[g];
    __shared__ uint lh[PBS / 4];
    for (int i = threadIdx.x; i < PBS / 4; i += 256) lh[i] = 0;
    __syncthreads();
    int e0 = b * CHE;
    for (int e = e0 + threadIdx.x; e < e0 + CHE; e += 256) {
        uint n = (uint)idx[e];
        atomicAdd(&lh[n >> 2], 1u << (8 * (n & 3)));   // LDS atomic only
    }
    __syncthreads();
    uint* out = (dir ? partD : partS) + (size_t)(g * NCH + b) * (PBS / 4);
    for (int i = threadIdx.x; i < PBS / 4; i += 256) out[i] = lh[i];
}

__global__ __launch_bounds__(256) void reduce_kernel(const uchar* __restrict__ partS,
                                                     uchar* __restrict__ partD,
                                                     float* __restrict__ ns,
                                                     float* __restrict__ nd,
                                                     int* __restrict__ degd) {
    int idx = blockIdx.x * 256 + threadIdx.x;
    if (idx >= 4 * NN) return;
    int g = idx / NN, n = idx - g * NN;
    const uchar* ps = partS + (size_t)(g * NCH) * PBS + n;
    uint ss = 0;
    for (int b = 0; b < NCH; b++) ss += ps[(size_t)b * PBS];
    uchar* pd = partD + (size_t)(g * NCH) * PBS + n;
    uint run = 0;
    for (int b = 0; b < NCH; b++) {
        uint v = pd[(size_t)b * PBS];
        pd[(size_t)b * PBS] = (uchar)run;
        run += v;
    }
    ns[idx] = rsqrtf((float)max(ss, 1u));
    nd[idx] = rsqrtf((float)max(run, 1u));
    degd[idx] = (int)run;
}

__global__ __launch_bounds__(1024) void scan1_kernel(const int* __restrict__ degd,
                                                     int* __restrict__ rs_all,
                                                     int* __restrict__ bsum) {
    int j = blockIdx.x, g = blockIdx.y;
    int i = j * 1024 + threadIdx.x;
    int v = (i < NN) ? degd[g * NN + i] : 0;
    int lane = threadIdx.x & 63, w = threadIdx.x >> 6;
    int x = v;
    #pragma unroll
    for (int off = 1; off < 64; off <<= 1) {
        int t = __shfl_up(x, off, 64);
        if (lane >= off) x += t;
    }
    __shared__ int ws[17];
    if (lane == 63) ws[w] = x;
    __syncthreads();
    if (threadIdx.x == 0) {
        int run = 0;
        #pragma unroll
        for (int k = 0; k < 16; k++) { int t = ws[k]; ws[k] = run; run += t; }
        ws[16] = run;
    }
    __syncthreads();
    if (i < NN) rs_all[g * (NN + 1) + i] = ws[w] + x - v;
    if (threadIdx.x == 0) bsum[g * SCB + j] = ws[16];
}

__global__ void scan2_kernel(int* __restrict__ bsum, int* __restrict__ rs_all) {
    int g = threadIdx.x >> 6, lane = threadIdx.x & 63;
    int v = (lane < SCB) ? bsum[g * SCB + lane] : 0;
    int x = v;
    #pragma unroll
    for (int off = 1; off < 64; off <<= 1) {
        int t = __shfl_up(x, off, 64);
        if (lane >= off) x += t;
    }
    if (lane < SCB) bsum[g * SCB + lane] = x - v;   // exclusive
    if (lane == 63) rs_all[g * (NN + 1) + NN] = x;  // total (== EN)
}

__global__ __launch_bounds__(1024) void scan3_kernel(const int* __restrict__ bsum,
                                                     int* __restrict__ rs_all) {
    int j = blockIdx.x, g = blockIdx.y;
    int i = j * 1024 + threadIdx.x;
    int off = bsum[g * SCB + j];
    if (i < NN) rs_all[g * (NN + 1) + i] += off;
}

__global__ __launch_bounds__(256) void scatter_kernel(GP src, GP dst,
                                                      const int* __restrict__ rs_all,
                                                      const uchar* __restrict__ pf,
                                                      ushort* __restrict__ csr) {
    int b = blockIdx.x, g = blockIdx.y;
    __shared__ uint lc[PBS / 4];
    for (int i = threadIdx.x; i < PBS / 4; i += 256) lc[i] = 0;
    __syncthreads();
    const int* sp = src.p[g];
    const int* dp = dst.p[g];
    const int* rs = rs_all + g * (NN + 1);
    const uchar* pfb = pf + (size_t)(g * NCH + b) * PBS;
    ushort* csrg = csr + (size_t)g * EN;
    int e0 = b * CHE;
    for (int e = e0 + threadIdx.x; e < e0 + CHE; e += 256) {
        uint d = (uint)dp[e];
        int s = sp[e];
        uint sh = 8 * (d & 3);
        uint old = atomicAdd(&lc[d >> 2], 1u << sh);
        uint r = (old >> sh) & 0xFFu;
        csrg[rs[d] + (int)pfb[d] + (int)r] = (ushort)s;
    }
}

// ---- degree counting sort -> perm (equal-degree nodes -> same wave) --------

__global__ __launch_bounds__(256) void dhist_kernel(const int* __restrict__ degd,
                                                    int* __restrict__ dh) {
    int g = blockIdx.y;
    __shared__ int lh[256];
    lh[threadIdx.x] = 0;
    __syncthreads();
    for (int i = blockIdx.x * 256 + threadIdx.x; i < NN; i += gridDim.x * 256) {
        int d = degd[g * NN + i];
        atomicAdd(&lh[d < 255 ? d : 255], 1);
    }
    __syncthreads();
    int v = lh[threadIdx.x];
    if (v) atomicAdd(&dh[g * 256 + threadIdx.x], v);
}

__global__ void dscan_kernel(const int* __restrict__ dh, int* __restrict__ dcur) {
    int tid = threadIdx.x, lane = tid & 63, w = tid >> 6;
    __shared__ int ws[4];
    for (int g = 0; g < 4; g++) {
        int v = dh[g * 256 + tid];
        int x = v;
        #pragma unroll
        for (int off = 1; off < 64; off <<= 1) {
            int t = __shfl_up(x, off, 64);
            if (lane >= off) x += t;
        }
        if (lane == 63) ws[w] = x;
        __syncthreads();
        int prefix = 0;
        for (int j = 0; j < w; j++) prefix += ws[j];
        dcur[g * 256 + tid] = prefix + x - v;
        __syncthreads();
    }
}

__global__ __launch_bounds__(256) void dscatter_kernel(const int* __restrict__ degd,
                                                       int* __restrict__ dcur,
                                                       int* __restrict__ perm) {
    int idx = blockIdx.x * 256 + threadIdx.x;
    if (idx >= 4 * NN) return;
    int g = idx / NN, n = idx - g * NN;
    int d = degd[idx]; d = d < 255 ? d : 255;
    int pos = atomicAdd(&dcur[g * 256 + d], 1);
    perm[g * NN + pos] = n;
}

// ---- weight transpose/pad to bf16: Wt[n][k], stride WS = K+8 ---------------

__global__ __launch_bounds__(256) void wtrans_kernel(const float* __restrict__ W,
                                                     ushort* __restrict__ Wt,
                                                     int Kreal, int WS) {
    int idx = blockIdx.x * 256 + threadIdx.x;
    if (idx >= 320 * WS) return;
    int n = idx / WS, k = idx - n * WS;
    float v = (n < 304 && k < Kreal) ? W[k * 304 + n] : 0.f;
    Wt[idx] = f2bf(v);
}

// ---- prescale: xs = fp8(x * ns), sliced [4][NN][8 dwords] ------------------

__global__ __launch_bounds__(256) void prescale_kernel(const float* __restrict__ x,
                                                       const float* __restrict__ ns,
                                                       uint* __restrict__ xs) {
    int idx = blockIdx.x * 256 + threadIdx.x;   // over NN*16 uint2 units
    if (idx >= NN * 16) return;
    int row = idx >> 4, j = idx & 15;
    int sl = j >> 2, pos = j & 3;
    float nv = ns[row];
    float4 v0 = ((const float4*)x)[idx * 2];
    float4 v1 = ((const float4*)x)[idx * 2 + 1];
    int p0 = 0, p1 = 0;
    p0 = __builtin_amdgcn_cvt_pk_fp8_f32(v0.x * nv, v0.y * nv, p0, false);
    p0 = __builtin_amdgcn_cvt_pk_fp8_f32(v0.z * nv, v0.w * nv, p0, true);
    p1 = __builtin_amdgcn_cvt_pk_fp8_f32(v1.x * nv, v1.y * nv, p1, false);
    p1 = __builtin_amdgcn_cvt_pk_fp8_f32(v1.z * nv, v1.w * nv, p1, true);
    ((uint2*)xs)[(size_t)sl * NN * 4 + row * 4 + pos] = make_uint2((uint)p0, (uint)p1);
}

// ---- SpMM (sliced, group-owns-node, degree-sorted, unroll-4) ---------------

// xs: 4 slices x [NN][8 dw]. Wave = 8 groups x 8 lanes. Grid (4, ceil(NN/32)).
__global__ __launch_bounds__(256) void spmm128_kernel(const uint* __restrict__ xs,
                                                      const int* __restrict__ rs,
                                                      const ushort* __restrict__ csr,
                                                      const float* __restrict__ nd,
                                                      const int* __restrict__ perm,
                                                      uint* __restrict__ out) {
    int wv = threadIdx.x >> 6, lane = threadIdx.x & 63;
    int grp = lane >> 3, gl = lane & 7;
    int slot = blockIdx.y * 32 + wv * 8 + grp;
    int sl = blockIdx.x;
    const uint* base = xs + (size_t)sl * NN * 8;
    bool ok = slot < NN;
    int node = ok ? perm[slot] : 0;
    int e0 = ok ? rs[node] : 0, e1 = ok ? rs[node + 1] : 0;
    float a0 = 0.f, a1 = 0.f, a2 = 0.f, a3 = 0.f;
    float b0 = 0.f, b1 = 0.f, b2 = 0.f, b3 = 0.f;
    int e = e0;
    for (; e + 4 <= e1; e += 4) {
        int s0 = csr[e], s1 = csr[e + 1], s2 = csr[e + 2], s3 = csr[e + 3];
        uint d0 = base[(size_t)s0 * 8 + gl];
        uint d1 = base[(size_t)s1 * 8 + gl];
        uint d2 = base[(size_t)s2 * 8 + gl];
        uint d3 = base[(size_t)s3 * 8 + gl];
        f2v l0 = __builtin_amdgcn_cvt_pk_f32_fp8(d0, false);
        f2v h0 = __builtin_amdgcn_cvt_pk_f32_fp8(d0, true);
        f2v l1 = __builtin_amdgcn_cvt_pk_f32_fp8(d1, false);
        f2v h1 = __builtin_amdgcn_cvt_pk_f32_fp8(d1, true);
        f2v l2 = __builtin_amdgcn_cvt_pk_f32_fp8(d2, false);
        f2v h2 = __builtin_amdgcn_cvt_pk_f32_fp8(d2, true);
        f2v l3 = __builtin_amdgcn_cvt_pk_f32_fp8(d3, false);
        f2v h3 = __builtin_amdgcn_cvt_pk_f32_fp8(d3, true);
        a0 += l0[0] + l1[0]; a1 += l0[1] + l1[1];
        a2 += h0[0] + h1[0]; a3 += h0[1] + h1[1];
        b0 += l2[0] + l3[0]; b1 += l2[1] + l3[1];
        b2 += h2[0] + h3[0]; b3 += h2[1] + h3[1];
    }
    for (; e < e1; e++) {
        int s = csr[e];
        uint d = base[(size_t)s * 8 + gl];
        f2v lo = __builtin_amdgcn_cvt_pk_f32_fp8(d, false);
        f2v hi = __builtin_amdgcn_cvt_pk_f32_fp8(d, true);
        a0 += lo[0]; a1 += lo[1]; a2 += hi[0]; a3 += hi[1];
    }
    a0 += b0; a1 += b1; a2 += b2; a3 += b3;
    if (ok) {
        float nv = nd[node];
        ((uint2*)out)[(size_t)node * 32 + sl * 8 + gl] =
            make_uint2(pk2(a0 * nv, a1 * nv), pk2(a2 * nv, a3 * nv));
    }
}

// hs: 8 slices x [NN][10 dw]. Wave = 6 groups x 10 lanes (lanes 60-63 idle).
// Grid (8, ceil(NN/24)).
__global__ __launch_bounds__(256) void spmm320_kernel(const uint* __restrict__ hs,
                                                      const int* __restrict__ rs,
                                                      const ushort* __restrict__ csr,
                                                      const float* __restrict__ nd,
                                                      const int* __restrict__ perm,
                                                      uint* __restrict__ out) {
    int wv = threadIdx.x >> 6, lane = threadIdx.x & 63;
    int grp = lane / 10;             // 0..5 active, 6 idle
    int gl = lane - grp * 10;
    int slot = blockIdx.y * 24 + wv * 6 + grp;
    int sl = blockIdx.x;
    const uint* base = hs + (size_t)sl * NN * 10;
    bool ok = (grp < 6) && (slot < NN);
    int node = ok ? perm[slot] : 0;
    int e0 = ok ? rs[node] : 0, e1 = ok ? rs[node + 1] : 0;
    float a0 = 0.f, a1 = 0.f, a2 = 0.f, a3 = 0.f;
    float b0 = 0.f, b1 = 0.f, b2 = 0.f, b3 = 0.f;
    int e = e0;
    for (; e + 4 <= e1; e += 4) {
        int s0 = csr[e], s1 = csr[e + 1], s2 = csr[e + 2], s3 = csr[e + 3];
        uint d0 = base[(size_t)s0 * 10 + gl];
        uint d1 = base[(size_t)s1 * 10 + gl];
        uint d2 = base[(size_t)s2 * 10 + gl];
        uint d3 = base[(size_t)s3 * 10 + gl];
        f2v l0 = __builtin_amdgcn_cvt_pk_f32_fp8(d0, false);
        f2v h0 = __builtin_amdgcn_cvt_pk_f32_fp8(d0, true);
        f2v l1 = __builtin_amdgcn_cvt_pk_f32_fp8(d1, false);
        f2v h1 = __builtin_amdgcn_cvt_pk_f32_fp8(d1, true);
        f2v l2 = __builtin_amdgcn_cvt_pk_f32_fp8(d2, false);
        f2v h2 = __builtin_amdgcn_cvt_pk_f32_fp8(d2, true);
        f2v l3 = __builtin_amdgcn_cvt_pk_f32_fp8(d3, false);
        f2v h3 = __builtin_amdgcn_cvt_pk_f32_fp8(d3, true);
        a0 += l0[0] + l1[0]; a1 += l0[1] + l1[1];
        a2 += h0[0] + h1[0]; a3 += h0[1] + h1[1];
        b0 += l2[0] + l3[0]; b1 += l2[1] + l3[1];
        b2 += h2[0] + h3[0]; b3 += h2[1] + h3[1];
    }
    for (; e < e1; e++) {
        int s = csr[e];
        uint d = base[(size_t)s * 10 + gl];
        f2v lo = __builtin_amdgcn_cvt_pk_f32_fp8(d, false);
        f2v hi = __builtin_amdgcn_cvt_pk_f32_fp8(d, true);
        a0 += lo[0]; a1 += lo[1]; a2 += hi[0]; a3 += hi[1];
    }
    a0 += b0; a1 += b1; a2 += b2; a3 += b3;
    if (ok) {
        float nv = nd[node];
        ((uint2*)out)[(size_t)node * 80 + sl * 10 + gl] =
            make_uint2(pk2(a0 * nv, a1 * nv), pk2(a2 * nv, a3 * nv));
    }
}

// ---- GEMM: C[M x 320] = A[M x K] @ Wt^T, epilogue relu(+bias) --------------

template<int KSTEPS, bool REDUCE>
__global__ __launch_bounds__(256) void gemm_kernel(const ushort* __restrict__ A, int astride,
                                                   const ushort* __restrict__ Wt,
                                                   const float* __restrict__ bias,
                                                   const float* __restrict__ ns,
                                                   uchar* __restrict__ Hout,
                                                   double* __restrict__ accum,
                                                   int M) {
    constexpr int K = KSTEPS * 32;
    constexpr int WS = K + 8;   // pad: 2-way LDS conflicts only (free)
    __shared__ __align__(16) ushort wt[80 * WS];
    __shared__ float redbuf[4];
    int tid = threadIdx.x, lane = tid & 63, wv = tid >> 6;
    int nb = blockIdx.y * 80;
    int r0 = blockIdx.x * 128 + wv * 32;

    {   // stage 80 rows of Wt (16B vectors)
        const s8v* src = (const s8v*)(Wt + (size_t)nb * WS);
        s8v* dst = (s8v*)wt;
        for (int i = tid; i < 80 * WS / 8; i += 256) dst[i] = src[i];
    }
    __syncthreads();

    f4v acc[2][5];
    #pragma unroll
    for (int t = 0; t < 2; t++)
        #pragma unroll
        for (int j = 0; j < 5; j++) acc[t][j] = (f4v){0.f, 0.f, 0.f, 0.f};

    int m15 = lane & 15;
    int kq = (lane >> 4) * 8;
    int ar0 = min(r0 + m15, M - 1);
    int ar1 = min(r0 + 16 + m15, M - 1);
    const ushort* a0p = A + (size_t)ar0 * astride + kq;
    const ushort* a1p = A + (size_t)ar1 * astride + kq;
    const ushort* bb = wt + (size_t)m15 * WS + kq;

    #pragma unroll
    for (int ks = 0; ks < KSTEPS; ks++) {
        s8v af0 = *(const s8v*)(a0p + ks * 32);
        s8v af1 = *(const s8v*)(a1p + ks * 32);
        #pragma unroll
        for (int nt = 0; nt < 5; nt++) {
            s8v bf = *(const s8v*)(bb + nt * 16 * WS + ks * 32);
            acc[0][nt] = mfma16(af0, bf, acc[0][nt]);
            acc[1][nt] = mfma16(af1, bf, acc[1][nt]);
        }
    }

    int rq = (lane >> 4) * 4;   // C/D: col = lane&15, row = (lane>>4)*4 + reg
    if constexpr (!REDUCE) {
        float nsv[2][4];
        #pragma unroll
        for (int t = 0; t < 2; t++)
            #pragma unroll
            for (int r = 0; r < 4; r++) {
                int row = r0 + t * 16 + rq + r;
                nsv[t][r] = (row < M) ? ns[row] : 0.f;
            }
        #pragma unroll
        for (int nt = 0; nt < 5; nt++) {
            int col = nb + nt * 16 + m15;
            float bv = (col < 304) ? bias[col] : 0.f;
            int sl = col / 40, cw = col - sl * 40;
            uchar* hp = Hout + (size_t)sl * NN * 40 + cw;
            #pragma unroll
            for (int t = 0; t < 2; t++)
                #pragma unroll
                for (int r = 0; r < 4; r++) {
                    int row = r0 + t * 16 + rq + r;
                    if (row < M) {
                        float y = fmaxf(acc[t][nt][r] + bv, 0.f) * nsv[t][r];
                        hp[(size_t)row * 40] = f2fp8(y);
                    }
                }
        }
    } else {
        float s = 0.f;
        #pragma unroll
        for (int nt = 0; nt < 5; nt++) {
            int col = nb + nt * 16 + m15;
            float bv = (col < 304) ? bias[col] : 0.f;
            #pragma unroll
            for (int t = 0; t < 2; t++)
                #pragma unroll
                for (int r = 0; r < 4; r++) {
                    int row = r0 + t * 16 + rq + r;
                    if (row < M && col < 304) s += fmaxf(acc[t][nt][r] + bv, 0.f);
                }
        }
        #pragma unroll
        for (int off = 32; off; off >>= 1) s += __shfl_xor(s, off, 64);
        if (lane == 0) redbuf[wv] = s;
        __syncthreads();
        if (tid == 0) {
            double b = (double)redbuf[0] + redbuf[1] + redbuf[2] + redbuf[3];
            atomicAdd(accum, b);
        }
    }
}

__global__ void finalize_kernel(const double* __restrict__ accum, float* __restrict__ out) {
    out[0] = (float)(accum[0] / (double)(4.0 * NN * 304.0));
}

// ---- host ------------------------------------------------------------------

extern "C" void kernel_launch(void* const* d_in, const int* in_sizes, int n_in,
                              void* d_out, int out_size, void* d_ws, size_t ws_size,
                              hipStream_t stream) {
    char* w = (char*)d_ws;
    auto alloc = [&](size_t bytes) {
        char* p = w;
        w += (bytes + 255) & ~(size_t)255;
        return p;
    };
    double* accum  = (double*)alloc(256);
    int*    degd   = (int*)alloc((size_t)4 * NN * 4);
    int*    rs     = (int*)alloc((size_t)4 * (NN + 1) * 4);
    int*    bsum   = (int*)alloc((size_t)4 * SCB * 4);
    float*  nsrc   = (float*)alloc((size_t)4 * NN * 4);
    float*  ndst   = (float*)alloc((size_t)4 * NN * 4);
    ushort* csr    = (ushort*)alloc((size_t)4 * EN * 2);       // u16 src ids
    int*    dh     = (int*)alloc((size_t)4 * 256 * 4);
    int*    dcur   = (int*)alloc((size_t)4 * 256 * 4);
    int*    perm   = (int*)alloc((size_t)4 * NN * 4);
    ushort* wt1    = (ushort*)alloc((size_t)320 * 136 * 2);
    ushort* wt2    = (ushort*)alloc((size_t)320 * 328 * 2);
    ushort* wt3    = (ushort*)alloc((size_t)320 * 328 * 2);
    uint*   partS  = (uint*)alloc((size_t)4 * NCH * PBS);      // 12.8 MB
    uint*   partD  = (uint*)alloc((size_t)4 * NCH * PBS);      // 12.8 MB
    uint*   hbuf   = (uint*)alloc((size_t)NN * 80 * 4);        // fp8 8-slice N x 320
    uint*   mbuf   = (uint*)alloc((size_t)NN * 160 * 4);       // bf16 N x 320
    // partS/partD dead after scatter: alias layer-1 buffers onto them.
    uint*   xs     = partS;   // fp8 4-slice N x 128: 6.4 MB  <= 12.8 MB
    uint*   m1     = partD;   // bf16 N x 128: 12.8 MB <= 12.8 MB

    hipMemsetAsync(accum, 0, 256, stream);
    hipMemsetAsync(dh, 0, (size_t)4 * 256 * 4, stream);

    wtrans_kernel<<<(320 * 136 + 255) / 256, 256, 0, stream>>>((const float*)d_in[12], wt1, 128, 136);
    wtrans_kernel<<<(320 * 328 + 255) / 256, 256, 0, stream>>>((const float*)d_in[14], wt2, 304, 328);
    wtrans_kernel<<<(320 * 328 + 255) / 256, 256, 0, stream>>>((const float*)d_in[16], wt3, 304, 328);

    GP S, D;
    for (int g = 0; g < 4; g++) {
        S.p[g] = (const int*)d_in[1 + 3 * g];
        D.p[g] = (const int*)d_in[2 + 3 * g];
    }
    hist_kernel<<<dim3(NCH, 2, 4), 256, 0, stream>>>(S, D, partS, partD);
    reduce_kernel<<<(4 * NN + 255) / 256, 256, 0, stream>>>((const uchar*)partS, (uchar*)partD,
                                                            nsrc, ndst, degd);
    scan1_kernel<<<dim3(SCB, 4), 1024, 0, stream>>>(degd, rs, bsum);
    scan2_kernel<<<1, 256, 0, stream>>>(bsum, rs);
    scan3_kernel<<<dim3(SCB, 4), 1024, 0, stream>>>(bsum, rs);
    scatter_kernel<<<dim3(NCH, 4), 256, 0, stream>>>(S, D, rs, (const uchar*)partD, csr);
    dhist_kernel<<<dim3(13, 4), 256, 0, stream>>>(degd, dh);
    dscan_kernel<<<1, 256, 0, stream>>>(dh, dcur);
    dscatter_kernel<<<(4 * NN + 255) / 256, 256, 0, stream>>>(degd, dcur, perm);

    const float* b1 = (const float*)d_in[13];
    const float* b2 = (const float*)d_in[15];
    const float* b3 = (const float*)d_in[17];
    dim3 ggrid((NN + 127) / 128, 4);

    for (int g = 0; g < 4; g++) {
        const float* xin = (const float*)d_in[3 * g];
        const float* nsg = nsrc + g * NN;
        const float* ndg = ndst + g * NN;
        const int* rsg = rs + g * (NN + 1);
        const ushort* csrg = csr + (size_t)g * EN;
        const int* permg = perm + g * NN;

        prescale_kernel<<<(NN * 16 + 255) / 256, 256, 0, stream>>>(xin, nsg, xs);
        spmm128_kernel<<<dim3(4, (NN + 31) / 32), 256, 0, stream>>>(xs, rsg, csrg, ndg, permg, m1);
        gemm_kernel<4, false><<<ggrid, 256, 0, stream>>>((const ushort*)m1, 128, wt1, b1, nsg,
                                                         (uchar*)hbuf, nullptr, NN);
        spmm320_kernel<<<dim3(8, (NN + 23) / 24), 256, 0, stream>>>(hbuf, rsg, csrg, ndg, permg, mbuf);
        gemm_kernel<10, false><<<ggrid, 256, 0, stream>>>((const ushort*)mbuf, 320, wt2, b2, nsg,
                                                          (uchar*)hbuf, nullptr, NN);
        spmm320_kernel<<<dim3(8, (NN + 23) / 24), 256, 0, stream>>>(hbuf, rsg, csrg, ndg, permg, mbuf);
        gemm_kernel<10, true><<<ggrid, 256, 0, stream>>>((const ushort*)mbuf, 320, wt3, b3, nullptr,
                                                         nullptr, accum, NN);
    }
    finalize_kernel<<<1, 1, 0, stream>>>(accum, (float*)d_out);
}

// Round 7
// 1404.183 us; speedup vs baseline: 1.4482x; 1.1325x over previous
//
#include <hip/hip_runtime.h>
#include <hip/hip_bf16.h>

// GCN1: 3-layer GraphConv x 4 graphs -> scalar grand mean.
// R7: degree counting sort made chunked/atomic-free (R6's dscatter was 183us
// of hot-counter atomic serialization). Per-chunk 256-bin LDS hists ->
// partials -> prefix kernel -> LDS-cursor scatter; zero global atomics.
// SpMM = XCD-sliced fp8 gathers, group-owns-node, degree-sorted, unroll-4.
// csr u16; CSR build atomic-free; MFMA bf16 GEMMs; layer-3 GEMM reduces
// relu(y) straight into a double accumulator.

#define NN 50000
#define EN 800000
#define NCH 64            // CSR chunks per graph
#define CHE 12500         // edges per chunk (NCH*CHE == EN)
#define PBS 50016         // padded per-chunk histogram bytes (>= NN, %4==0)
#define SCB 49            // scan blocks per graph (49*1024 >= NN)
#define DCH 13            // degree-sort chunks per graph
#define DCN 4096          // nodes per degree-sort chunk (13*4096 >= NN)

typedef unsigned int uint;
typedef unsigned short ushort;
typedef unsigned char uchar;
typedef short s8v __attribute__((ext_vector_type(8)));
typedef float f4v __attribute__((ext_vector_type(4)));
typedef float f2v __attribute__((ext_vector_type(2)));

__device__ inline ushort f2bf(float f) {
    uint u = __float_as_uint(f);
    uint r = (u + 0x7FFFu + ((u >> 16) & 1u)) >> 16;
    return (ushort)r;
}
__device__ inline uint pk2(float lo, float hi) {
    return (uint)f2bf(lo) | ((uint)f2bf(hi) << 16);
}
__device__ inline f4v mfma16(s8v a, s8v b, f4v c) {
    return __builtin_amdgcn_mfma_f32_16x16x32_bf16(a, b, c, 0, 0, 0);
}
__device__ inline uchar f2fp8(float f) {
    return (uchar)(__builtin_amdgcn_cvt_pk_fp8_f32(f, 0.f, 0, false) & 0xFF);
}

struct GP { const int* p[4]; };

// ---- CSR build (atomic-free) ----------------------------------------------

__global__ __launch_bounds__(256) void hist_kernel(GP src, GP dst,
                                                   uint* __restrict__ partS,
                                                   uint* __restrict__ partD) {
    int b = blockIdx.x, dir = blockIdx.y, g = blockIdx.z;
    const int* idx = dir ? dst.p[g] : src.p[g];
    __shared__ uint lh[PBS / 4];
    for (int i = threadIdx.x; i < PBS / 4; i += 256) lh[i] = 0;
    __syncthreads();
    int e0 = b * CHE;
    for (int e = e0 + threadIdx.x; e < e0 + CHE; e += 256) {
        uint n = (uint)idx[e];
        atomicAdd(&lh[n >> 2], 1u << (8 * (n & 3)));   // LDS atomic only
    }
    __syncthreads();
    uint* out = (dir ? partD : partS) + (size_t)(g * NCH + b) * (PBS / 4);
    for (int i = threadIdx.x; i < PBS / 4; i += 256) out[i] = lh[i];
}

__global__ __launch_bounds__(256) void reduce_kernel(const uchar* __restrict__ partS,
                                                     uchar* __restrict__ partD,
                                                     float* __restrict__ ns,
                                                     float* __restrict__ nd,
                                                     int* __restrict__ degd) {
    int idx = blockIdx.x * 256 + threadIdx.x;
    if (idx >= 4 * NN) return;
    int g = idx / NN, n = idx - g * NN;
    const uchar* ps = partS + (size_t)(g * NCH) * PBS + n;
    uint ss = 0;
    for (int b = 0; b < NCH; b++) ss += ps[(size_t)b * PBS];
    uchar* pd = partD + (size_t)(g * NCH) * PBS + n;
    uint run = 0;
    for (int b = 0; b < NCH; b++) {
        uint v = pd[(size_t)b * PBS];
        pd[(size_t)b * PBS] = (uchar)run;
        run += v;
    }
    ns[idx] = rsqrtf((float)max(ss, 1u));
    nd[idx] = rsqrtf((float)max(run, 1u));
    degd[idx] = (int)run;
}

__global__ __launch_bounds__(1024) void scan1_kernel(const int* __restrict__ degd,
                                                     int* __restrict__ rs_all,
                                                     int* __restrict__ bsum) {
    int j = blockIdx.x, g = blockIdx.y;
    int i = j * 1024 + threadIdx.x;
    int v = (i < NN) ? degd[g * NN + i] : 0;
    int lane = threadIdx.x & 63, w = threadIdx.x >> 6;
    int x = v;
    #pragma unroll
    for (int off = 1; off < 64; off <<= 1) {
        int t = __shfl_up(x, off, 64);
        if (lane >= off) x += t;
    }
    __shared__ int ws[17];
    if (lane == 63) ws[w] = x;
    __syncthreads();
    if (threadIdx.x == 0) {
        int run = 0;
        #pragma unroll
        for (int k = 0; k < 16; k++) { int t = ws[k]; ws[k] = run; run += t; }
        ws[16] = run;
    }
    __syncthreads();
    if (i < NN) rs_all[g * (NN + 1) + i] = ws[w] + x - v;
    if (threadIdx.x == 0) bsum[g * SCB + j] = ws[16];
}

__global__ void scan2_kernel(int* __restrict__ bsum, int* __restrict__ rs_all) {
    int g = threadIdx.x >> 6, lane = threadIdx.x & 63;
    int v = (lane < SCB) ? bsum[g * SCB + lane] : 0;
    int x = v;
    #pragma unroll
    for (int off = 1; off < 64; off <<= 1) {
        int t = __shfl_up(x, off, 64);
        if (lane >= off) x += t;
    }
    if (lane < SCB) bsum[g * SCB + lane] = x - v;   // exclusive
    if (lane == 63) rs_all[g * (NN + 1) + NN] = x;  // total (== EN)
}

__global__ __launch_bounds__(1024) void scan3_kernel(const int* __restrict__ bsum,
                                                     int* __restrict__ rs_all) {
    int j = blockIdx.x, g = blockIdx.y;
    int i = j * 1024 + threadIdx.x;
    int off = bsum[g * SCB + j];
    if (i < NN) rs_all[g * (NN + 1) + i] += off;
}

__global__ __launch_bounds__(256) void scatter_kernel(GP src, GP dst,
                                                      const int* __restrict__ rs_all,
                                                      const uchar* __restrict__ pf,
                                                      ushort* __restrict__ csr) {
    int b = blockIdx.x, g = blockIdx.y;
    __shared__ uint lc[PBS / 4];
    for (int i = threadIdx.x; i < PBS / 4; i += 256) lc[i] = 0;
    __syncthreads();
    const int* sp = src.p[g];
    const int* dp = dst.p[g];
    const int* rs = rs_all + g * (NN + 1);
    const uchar* pfb = pf + (size_t)(g * NCH + b) * PBS;
    ushort* csrg = csr + (size_t)g * EN;
    int e0 = b * CHE;
    for (int e = e0 + threadIdx.x; e < e0 + CHE; e += 256) {
        uint d = (uint)dp[e];
        int s = sp[e];
        uint sh = 8 * (d & 3);
        uint old = atomicAdd(&lc[d >> 2], 1u << sh);
        uint r = (old >> sh) & 0xFFu;
        csrg[rs[d] + (int)pfb[d] + (int)r] = (ushort)s;
    }
}

// ---- degree counting sort (chunked, atomic-free) -> perm -------------------

__global__ __launch_bounds__(256) void dhist_kernel(const int* __restrict__ degd,
                                                    int* __restrict__ dhp) {
    int b = blockIdx.x, g = blockIdx.y;
    __shared__ int lh[256];
    lh[threadIdx.x] = 0;
    __syncthreads();
    int n0 = b * DCN, nend = min(n0 + DCN, NN);
    for (int i = n0 + threadIdx.x; i < nend; i += 256) {
        int d = degd[g * NN + i];
        atomicAdd(&lh[d < 255 ? d : 255], 1);   // LDS only
    }
    __syncthreads();
    dhp[(g * DCH + b) * 256 + threadIdx.x] = lh[threadIdx.x];
}

// dhp -> per-chunk exclusive prefix within each bin; dbase = bin base offsets.
__global__ void dscan_kernel(int* __restrict__ dhp, int* __restrict__ dbase) {
    int tid = threadIdx.x, lane = tid & 63, w = tid >> 6;
    __shared__ int ws[4];
    for (int g = 0; g < 4; g++) {
        int run = 0;
        for (int c = 0; c < DCH; c++) {
            int v = dhp[(g * DCH + c) * 256 + tid];
            dhp[(g * DCH + c) * 256 + tid] = run;
            run += v;
        }
        int x = run;
        #pragma unroll
        for (int off = 1; off < 64; off <<= 1) {
            int t = __shfl_up(x, off, 64);
            if (lane >= off) x += t;
        }
        if (lane == 63) ws[w] = x;
        __syncthreads();
        int prefix = 0;
        for (int j = 0; j < w; j++) prefix += ws[j];
        dbase[g * 256 + tid] = prefix + x - run;
        __syncthreads();
    }
}

__global__ __launch_bounds__(256) void dscatter_kernel(const int* __restrict__ degd,
                                                       const int* __restrict__ dhp,
                                                       const int* __restrict__ dbase,
                                                       int* __restrict__ perm) {
    int b = blockIdx.x, g = blockIdx.y;
    __shared__ int lc[256];
    lc[threadIdx.x] = 0;
    __syncthreads();
    int n0 = b * DCN, nend = min(n0 + DCN, NN);
    for (int i = n0 + threadIdx.x; i < nend; i += 256) {
        int d = degd[g * NN + i];
        d = d < 255 ? d : 255;
        int r = atomicAdd(&lc[d], 1);   // LDS only: within-chunk rank
        int pos = dbase[g * 256 + d] + dhp[(g * DCH + b) * 256 + d] + r;
        perm[g * NN + pos] = i;
    }
}

// ---- weight transpose/pad to bf16: Wt[n][k], stride WS = K+8 ---------------

__global__ __launch_bounds__(256) void wtrans_kernel(const float* __restrict__ W,
                                                     ushort* __restrict__ Wt,
                                                     int Kreal, int WS) {
    int idx = blockIdx.x * 256 + threadIdx.x;
    if (idx >= 320 * WS) return;
    int n = idx / WS, k = idx - n * WS;
    float v = (n < 304 && k < Kreal) ? W[k * 304 + n] : 0.f;
    Wt[idx] = f2bf(v);
}

// ---- prescale: xs = fp8(x * ns), sliced [4][NN][8 dwords] ------------------

__global__ __launch_bounds__(256) void prescale_kernel(const float* __restrict__ x,
                                                       const float* __restrict__ ns,
                                                       uint* __restrict__ xs) {
    int idx = blockIdx.x * 256 + threadIdx.x;   // over NN*16 uint2 units
    if (idx >= NN * 16) return;
    int row = idx >> 4, j = idx & 15;
    int sl = j >> 2, pos = j & 3;
    float nv = ns[row];
    float4 v0 = ((const float4*)x)[idx * 2];
    float4 v1 = ((const float4*)x)[idx * 2 + 1];
    int p0 = 0, p1 = 0;
    p0 = __builtin_amdgcn_cvt_pk_fp8_f32(v0.x * nv, v0.y * nv, p0, false);
    p0 = __builtin_amdgcn_cvt_pk_fp8_f32(v0.z * nv, v0.w * nv, p0, true);
    p1 = __builtin_amdgcn_cvt_pk_fp8_f32(v1.x * nv, v1.y * nv, p1, false);
    p1 = __builtin_amdgcn_cvt_pk_fp8_f32(v1.z * nv, v1.w * nv, p1, true);
    ((uint2*)xs)[(size_t)sl * NN * 4 + row * 4 + pos] = make_uint2((uint)p0, (uint)p1);
}

// ---- SpMM (sliced, group-owns-node, degree-sorted, unroll-4) ---------------

__global__ __launch_bounds__(256) void spmm128_kernel(const uint* __restrict__ xs,
                                                      const int* __restrict__ rs,
                                                      const ushort* __restrict__ csr,
                                                      const float* __restrict__ nd,
                                                      const int* __restrict__ perm,
                                                      uint* __restrict__ out) {
    int wv = threadIdx.x >> 6, lane = threadIdx.x & 63;
    int grp = lane >> 3, gl = lane & 7;
    int slot = blockIdx.y * 32 + wv * 8 + grp;
    int sl = blockIdx.x;
    const uint* base = xs + (size_t)sl * NN * 8;
    bool ok = slot < NN;
    int node = ok ? perm[slot] : 0;
    int e0 = ok ? rs[node] : 0, e1 = ok ? rs[node + 1] : 0;
    float a0 = 0.f, a1 = 0.f, a2 = 0.f, a3 = 0.f;
    float b0 = 0.f, b1 = 0.f, b2 = 0.f, b3 = 0.f;
    int e = e0;
    for (; e + 4 <= e1; e += 4) {
        int s0 = csr[e], s1 = csr[e + 1], s2 = csr[e + 2], s3 = csr[e + 3];
        uint d0 = base[(size_t)s0 * 8 + gl];
        uint d1 = base[(size_t)s1 * 8 + gl];
        uint d2 = base[(size_t)s2 * 8 + gl];
        uint d3 = base[(size_t)s3 * 8 + gl];
        f2v l0 = __builtin_amdgcn_cvt_pk_f32_fp8(d0, false);
        f2v h0 = __builtin_amdgcn_cvt_pk_f32_fp8(d0, true);
        f2v l1 = __builtin_amdgcn_cvt_pk_f32_fp8(d1, false);
        f2v h1 = __builtin_amdgcn_cvt_pk_f32_fp8(d1, true);
        f2v l2 = __builtin_amdgcn_cvt_pk_f32_fp8(d2, false);
        f2v h2 = __builtin_amdgcn_cvt_pk_f32_fp8(d2, true);
        f2v l3 = __builtin_amdgcn_cvt_pk_f32_fp8(d3, false);
        f2v h3 = __builtin_amdgcn_cvt_pk_f32_fp8(d3, true);
        a0 += l0[0] + l1[0]; a1 += l0[1] + l1[1];
        a2 += h0[0] + h1[0]; a3 += h0[1] + h1[1];
        b0 += l2[0] + l3[0]; b1 += l2[1] + l3[1];
        b2 += h2[0] + h3[0]; b3 += h2[1] + h3[1];
    }
    for (; e < e1; e++) {
        int s = csr[e];
        uint d = base[(size_t)s * 8 + gl];
        f2v lo = __builtin_amdgcn_cvt_pk_f32_fp8(d, false);
        f2v hi = __builtin_amdgcn_cvt_pk_f32_fp8(d, true);
        a0 += lo[0]; a1 += lo[1]; a2 += hi[0]; a3 += hi[1];
    }
    a0 += b0; a1 += b1; a2 += b2; a3 += b3;
    if (ok) {
        float nv = nd[node];
        ((uint2*)out)[(size_t)node * 32 + sl * 8 + gl] =
            make_uint2(pk2(a0 * nv, a1 * nv), pk2(a2 * nv, a3 * nv));
    }
}

__global__ __launch_bounds__(256) void spmm320_kernel(const uint* __restrict__ hs,
                                                      const int* __restrict__ rs,
                                                      const ushort* __restrict__ csr,
                                                      const float* __restrict__ nd,
                                                      const int* __restrict__ perm,
                                                      uint* __restrict__ out) {
    int wv = threadIdx.x >> 6, lane = threadIdx.x & 63;
    int grp = lane / 10;             // 0..5 active, 6 idle
    int gl = lane - grp * 10;
    int slot = blockIdx.y * 24 + wv * 6 + grp;
    int sl = blockIdx.x;
    const uint* base = hs + (size_t)sl * NN * 10;
    bool ok = (grp < 6) && (slot < NN);
    int node = ok ? perm[slot] : 0;
    int e0 = ok ? rs[node] : 0, e1 = ok ? rs[node + 1] : 0;
    float a0 = 0.f, a1 = 0.f, a2 = 0.f, a3 = 0.f;
    float b0 = 0.f, b1 = 0.f, b2 = 0.f, b3 = 0.f;
    int e = e0;
    for (; e + 4 <= e1; e += 4) {
        int s0 = csr[e], s1 = csr[e + 1], s2 = csr[e + 2], s3 = csr[e + 3];
        uint d0 = base[(size_t)s0 * 10 + gl];
        uint d1 = base[(size_t)s1 * 10 + gl];
        uint d2 = base[(size_t)s2 * 10 + gl];
        uint d3 = base[(size_t)s3 * 10 + gl];
        f2v l0 = __builtin_amdgcn_cvt_pk_f32_fp8(d0, false);
        f2v h0 = __builtin_amdgcn_cvt_pk_f32_fp8(d0, true);
        f2v l1 = __builtin_amdgcn_cvt_pk_f32_fp8(d1, false);
        f2v h1 = __builtin_amdgcn_cvt_pk_f32_fp8(d1, true);
        f2v l2 = __builtin_amdgcn_cvt_pk_f32_fp8(d2, false);
        f2v h2 = __builtin_amdgcn_cvt_pk_f32_fp8(d2, true);
        f2v l3 = __builtin_amdgcn_cvt_pk_f32_fp8(d3, false);
        f2v h3 = __builtin_amdgcn_cvt_pk_f32_fp8(d3, true);
        a0 += l0[0] + l1[0]; a1 += l0[1] + l1[1];
        a2 += h0[0] + h1[0]; a3 += h0[1] + h1[1];
        b0 += l2[0] + l3[0]; b1 += l2[1] + l3[1];
        b2 += h2[0] + h3[0]; b3 += h2[1] + h3[1];
    }
    for (; e < e1; e++) {
        int s = csr[e];
        uint d = base[(size_t)s * 10 + gl];
        f2v lo = __builtin_amdgcn_cvt_pk_f32_fp8(d, false);
        f2v hi = __builtin_amdgcn_cvt_pk_f32_fp8(d, true);
        a0 += lo[0]; a1 += lo[1]; a2 += hi[0]; a3 += hi[1];
    }
    a0 += b0; a1 += b1; a2 += b2; a3 += b3;
    if (ok) {
        float nv = nd[node];
        ((uint2*)out)[(size_t)node * 80 + sl * 10 + gl] =
            make_uint2(pk2(a0 * nv, a1 * nv), pk2(a2 * nv, a3 * nv));
    }
}

// ---- GEMM: C[M x 320] = A[M x K] @ Wt^T, epilogue relu(+bias) --------------

template<int KSTEPS, bool REDUCE>
__global__ __launch_bounds__(256) void gemm_kernel(const ushort* __restrict__ A, int astride,
                                                   const ushort* __restrict__ Wt,
                                                   const float* __restrict__ bias,
                                                   const float* __restrict__ ns,
                                                   uchar* __restrict__ Hout,
                                                   double* __restrict__ accum,
                                                   int M) {
    constexpr int K = KSTEPS * 32;
    constexpr int WS = K + 8;   // pad: 2-way LDS conflicts only (free)
    __shared__ __align__(16) ushort wt[80 * WS];
    __shared__ float redbuf[4];
    int tid = threadIdx.x, lane = tid & 63, wv = tid >> 6;
    int nb = blockIdx.y * 80;
    int r0 = blockIdx.x * 128 + wv * 32;

    {   // stage 80 rows of Wt (16B vectors)
        const s8v* src = (const s8v*)(Wt + (size_t)nb * WS);
        s8v* dst = (s8v*)wt;
        for (int i = tid; i < 80 * WS / 8; i += 256) dst[i] = src[i];
    }
    __syncthreads();

    f4v acc[2][5];
    #pragma unroll
    for (int t = 0; t < 2; t++)
        #pragma unroll
        for (int j = 0; j < 5; j++) acc[t][j] = (f4v){0.f, 0.f, 0.f, 0.f};

    int m15 = lane & 15;
    int kq = (lane >> 4) * 8;
    int ar0 = min(r0 + m15, M - 1);
    int ar1 = min(r0 + 16 + m15, M - 1);
    const ushort* a0p = A + (size_t)ar0 * astride + kq;
    const ushort* a1p = A + (size_t)ar1 * astride + kq;
    const ushort* bb = wt + (size_t)m15 * WS + kq;

    #pragma unroll
    for (int ks = 0; ks < KSTEPS; ks++) {
        s8v af0 = *(const s8v*)(a0p + ks * 32);
        s8v af1 = *(const s8v*)(a1p + ks * 32);
        #pragma unroll
        for (int nt = 0; nt < 5; nt++) {
            s8v bf = *(const s8v*)(bb + nt * 16 * WS + ks * 32);
            acc[0][nt] = mfma16(af0, bf, acc[0][nt]);
            acc[1][nt] = mfma16(af1, bf, acc[1][nt]);
        }
    }

    int rq = (lane >> 4) * 4;   // C/D: col = lane&15, row = (lane>>4)*4 + reg
    if constexpr (!REDUCE) {
        float nsv[2][4];
        #pragma unroll
        for (int t = 0; t < 2; t++)
            #pragma unroll
            for (int r = 0; r < 4; r++) {
                int row = r0 + t * 16 + rq + r;
                nsv[t][r] = (row < M) ? ns[row] : 0.f;
            }
        #pragma unroll
        for (int nt = 0; nt < 5; nt++) {
            int col = nb + nt * 16 + m15;
            float bv = (col < 304) ? bias[col] : 0.f;
            int sl = col / 40, cw = col - sl * 40;
            uchar* hp = Hout + (size_t)sl * NN * 40 + cw;
            #pragma unroll
            for (int t = 0; t < 2; t++)
                #pragma unroll
                for (int r = 0; r < 4; r++) {
                    int row = r0 + t * 16 + rq + r;
                    if (row < M) {
                        float y = fmaxf(acc[t][nt][r] + bv, 0.f) * nsv[t][r];
                        hp[(size_t)row * 40] = f2fp8(y);
                    }
                }
        }
    } else {
        float s = 0.f;
        #pragma unroll
        for (int nt = 0; nt < 5; nt++) {
            int col = nb + nt * 16 + m15;
            float bv = (col < 304) ? bias[col] : 0.f;
            #pragma unroll
            for (int t = 0; t < 2; t++)
                #pragma unroll
                for (int r = 0; r < 4; r++) {
                    int row = r0 + t * 16 + rq + r;
                    if (row < M && col < 304) s += fmaxf(acc[t][nt][r] + bv, 0.f);
                }
        }
        #pragma unroll
        for (int off = 32; off; off >>= 1) s += __shfl_xor(s, off, 64);
        if (lane == 0) redbuf[wv] = s;
        __syncthreads();
        if (tid == 0) {
            double b = (double)redbuf[0] + redbuf[1] + redbuf[2] + redbuf[3];
            atomicAdd(accum, b);
        }
    }
}

__global__ void finalize_kernel(const double* __restrict__ accum, float* __restrict__ out) {
    out[0] = (float)(accum[0] / (double)(4.0 * NN * 304.0));
}

// ---- host ------------------------------------------------------------------

extern "C" void kernel_launch(void* const* d_in, const int* in_sizes, int n_in,
                              void* d_out, int out_size, void* d_ws, size_t ws_size,
                              hipStream_t stream) {
    char* w = (char*)d_ws;
    auto alloc = [&](size_t bytes) {
        char* p = w;
        w += (bytes + 255) & ~(size_t)255;
        return p;
    };
    double* accum  = (double*)alloc(256);
    int*    degd   = (int*)alloc((size_t)4 * NN * 4);
    int*    rs     = (int*)alloc((size_t)4 * (NN + 1) * 4);
    int*    bsum   = (int*)alloc((size_t)4 * SCB * 4);
    float*  nsrc   = (float*)alloc((size_t)4 * NN * 4);
    float*  ndst   = (float*)alloc((size_t)4 * NN * 4);
    ushort* csr    = (ushort*)alloc((size_t)4 * EN * 2);       // u16 src ids
    int*    dhp    = (int*)alloc((size_t)4 * DCH * 256 * 4);
    int*    dbase  = (int*)alloc((size_t)4 * 256 * 4);
    int*    perm   = (int*)alloc((size_t)4 * NN * 4);
    ushort* wt1    = (ushort*)alloc((size_t)320 * 136 * 2);
    ushort* wt2    = (ushort*)alloc((size_t)320 * 328 * 2);
    ushort* wt3    = (ushort*)alloc((size_t)320 * 328 * 2);
    uint*   partS  = (uint*)alloc((size_t)4 * NCH * PBS);      // 12.8 MB
    uint*   partD  = (uint*)alloc((size_t)4 * NCH * PBS);      // 12.8 MB
    uint*   hbuf   = (uint*)alloc((size_t)NN * 80 * 4);        // fp8 8-slice N x 320
    uint*   mbuf   = (uint*)alloc((size_t)NN * 160 * 4);       // bf16 N x 320
    // partS/partD dead after scatter: alias layer-1 buffers onto them.
    uint*   xs     = partS;   // fp8 4-slice N x 128: 6.4 MB  <= 12.8 MB
    uint*   m1     = partD;   // bf16 N x 128: 12.8 MB <= 12.8 MB

    hipMemsetAsync(accum, 0, 256, stream);

    wtrans_kernel<<<(320 * 136 + 255) / 256, 256, 0, stream>>>((const float*)d_in[12], wt1, 128, 136);
    wtrans_kernel<<<(320 * 328 + 255) / 256, 256, 0, stream>>>((const float*)d_in[14], wt2, 304, 328);
    wtrans_kernel<<<(320 * 328 + 255) / 256, 256, 0, stream>>>((const float*)d_in[16], wt3, 304, 328);

    GP S, D;
    for (int g = 0; g < 4; g++) {
        S.p[g] = (const int*)d_in[1 + 3 * g];
        D.p[g] = (const int*)d_in[2 + 3 * g];
    }
    hist_kernel<<<dim3(NCH, 2, 4), 256, 0, stream>>>(S, D, partS, partD);
    reduce_kernel<<<(4 * NN + 255) / 256, 256, 0, stream>>>((const uchar*)partS, (uchar*)partD,
                                                            nsrc, ndst, degd);
    scan1_kernel<<<dim3(SCB, 4), 1024, 0, stream>>>(degd, rs, bsum);
    scan2_kernel<<<1, 256, 0, stream>>>(bsum, rs);
    scan3_kernel<<<dim3(SCB, 4), 1024, 0, stream>>>(bsum, rs);
    scatter_kernel<<<dim3(NCH, 4), 256, 0, stream>>>(S, D, rs, (const uchar*)partD, csr);
    dhist_kernel<<<dim3(DCH, 4), 256, 0, stream>>>(degd, dhp);
    dscan_kernel<<<1, 256, 0, stream>>>(dhp, dbase);
    dscatter_kernel<<<dim3(DCH, 4), 256, 0, stream>>>(degd, dhp, dbase, perm);

    const float* b1 = (const float*)d_in[13];
    const float* b2 = (const float*)d_in[15];
    const float* b3 = (const float*)d_in[17];
    dim3 ggrid((NN + 127) / 128, 4);

    for (int g = 0; g < 4; g++) {
        const float* xin = (const float*)d_in[3 * g];
        const float* nsg = nsrc + g * NN;
        const float* ndg = ndst + g * NN;
        const int* rsg = rs + g * (NN + 1);
        const ushort* csrg = csr + (size_t)g * EN;
        const int* permg = perm + g * NN;

        prescale_kernel<<<(NN * 16 + 255) / 256, 256, 0, stream>>>(xin, nsg, xs);
        spmm128_kernel<<<dim3(4, (NN + 31) / 32), 256, 0, stream>>>(xs, rsg, csrg, ndg, permg, m1);
        gemm_kernel<4, false><<<ggrid, 256, 0, stream>>>((const ushort*)m1, 128, wt1, b1, nsg,
                                                         (uchar*)hbuf, nullptr, NN);
        spmm320_kernel<<<dim3(8, (NN + 23) / 24), 256, 0, stream>>>(hbuf, rsg, csrg, ndg, permg, mbuf);
        gemm_kernel<10, false><<<ggrid, 256, 0, stream>>>((const ushort*)mbuf, 320, wt2, b2, nsg,
                                                          (uchar*)hbuf, nullptr, NN);
        spmm320_kernel<<<dim3(8, (NN + 23) / 24), 256, 0, stream>>>(hbuf, rsg, csrg, ndg, permg, mbuf);
        gemm_kernel<10, true><<<ggrid, 256, 0, stream>>>((const ushort*)mbuf, 320, wt3, b3, nullptr,
                                                         nullptr, accum, NN);
    }
    finalize_kernel<<<1, 1, 0, stream>>>(accum, (float*)d_out);
}

// Round 8
// 1377.735 us; speedup vs baseline: 1.4760x; 1.0192x over previous
//
#include <hip/hip_runtime.h>
#include <hip/hip_bf16.h>

// GCN1: 3-layer GraphConv x 4 graphs -> scalar grand mean.
// R8: SpMM line-throughput attack. Slice rows padded to 64B (hbuf) / kept
// 32B (xs) so every group-gather is exactly 1 cache line; groups shrunk to
// 5x8B / 4x8B lanes (12 / 16 nodes per wave). CSR padded to 4-edge alignment
// with pad edges pointing at an appended all-zero row (id NN) -> inner loop
// reads 4 edges per single 8B load, no tail, no bounds checks. Degree-sorted
// perm keeps trip counts wave-uniform. XCD-sliced fp8 gathers; atomic-free
// CSR build + degree sort; MFMA bf16 GEMMs; layer-3 GEMM reduces into double.

#define NN 50000
#define EN 800000
#define PEN 950000        // padded edges per graph (EN + 3*NN upper bound)
#define NCH 64            // CSR chunks per graph
#define CHE 12500         // edges per chunk (NCH*CHE == EN)
#define PBS 50016         // padded per-chunk histogram bytes (>= NN, %4==0)
#define SCB 49            // scan blocks per graph (49*1024 >= NN)
#define DCH 13            // degree-sort chunks per graph
#define DCN 4096          // nodes per degree-sort chunk (13*4096 >= NN)

typedef unsigned int uint;
typedef unsigned short ushort;
typedef unsigned char uchar;
typedef short s8v __attribute__((ext_vector_type(8)));
typedef float f4v __attribute__((ext_vector_type(4)));
typedef float f2v __attribute__((ext_vector_type(2)));

__device__ inline ushort f2bf(float f) {
    uint u = __float_as_uint(f);
    uint r = (u + 0x7FFFu + ((u >> 16) & 1u)) >> 16;
    return (ushort)r;
}
__device__ inline uint pk2(float lo, float hi) {
    return (uint)f2bf(lo) | ((uint)f2bf(hi) << 16);
}
__device__ inline f4v mfma16(s8v a, s8v b, f4v c) {
    return __builtin_amdgcn_mfma_f32_16x16x32_bf16(a, b, c, 0, 0, 0);
}
__device__ inline uchar f2fp8(float f) {
    return (uchar)(__builtin_amdgcn_cvt_pk_fp8_f32(f, 0.f, 0, false) & 0xFF);
}
__device__ inline void acc8(uint2 d, float* a) {
    f2v l0 = __builtin_amdgcn_cvt_pk_f32_fp8(d.x, false);
    f2v h0 = __builtin_amdgcn_cvt_pk_f32_fp8(d.x, true);
    f2v l1 = __builtin_amdgcn_cvt_pk_f32_fp8(d.y, false);
    f2v h1 = __builtin_amdgcn_cvt_pk_f32_fp8(d.y, true);
    a[0] += l0[0]; a[1] += l0[1]; a[2] += h0[0]; a[3] += h0[1];
    a[4] += l1[0]; a[5] += l1[1]; a[6] += h1[0]; a[7] += h1[1];
}

struct GP { const int* p[4]; };

// ---- CSR build (atomic-free) ----------------------------------------------

__global__ __launch_bounds__(256) void hist_kernel(GP src, GP dst,
                                                   uint* __restrict__ partS,
                                                   uint* __restrict__ partD) {
    int b = blockIdx.x, dir = blockIdx.y, g = blockIdx.z;
    const int* idx = dir ? dst.p[g] : src.p[g];
    __shared__ uint lh[PBS / 4];
    for (int i = threadIdx.x; i < PBS / 4; i += 256) lh[i] = 0;
    __syncthreads();
    int e0 = b * CHE;
    for (int e = e0 + threadIdx.x; e < e0 + CHE; e += 256) {
        uint n = (uint)idx[e];
        atomicAdd(&lh[n >> 2], 1u << (8 * (n & 3)));   // LDS atomic only
    }
    __syncthreads();
    uint* out = (dir ? partD : partS) + (size_t)(g * NCH + b) * (PBS / 4);
    for (int i = threadIdx.x; i < PBS / 4; i += 256) out[i] = lh[i];
}

__global__ __launch_bounds__(256) void reduce_kernel(const uchar* __restrict__ partS,
                                                     uchar* __restrict__ partD,
                                                     float* __restrict__ ns,
                                                     float* __restrict__ nd,
                                                     int* __restrict__ degd) {
    int idx = blockIdx.x * 256 + threadIdx.x;
    if (idx >= 4 * NN) return;
    int g = idx / NN, n = idx - g * NN;
    const uchar* ps = partS + (size_t)(g * NCH) * PBS + n;
    uint ss = 0;
    for (int b = 0; b < NCH; b++) ss += ps[(size_t)b * PBS];
    uchar* pd = partD + (size_t)(g * NCH) * PBS + n;
    uint run = 0;
    for (int b = 0; b < NCH; b++) {
        uint v = pd[(size_t)b * PBS];
        pd[(size_t)b * PBS] = (uchar)run;
        run += v;
    }
    ns[idx] = rsqrtf((float)max(ss, 1u));
    nd[idx] = rsqrtf((float)max(run, 1u));
    degd[idx] = (int)run;
}

// scan over PADDED degree (deg+3)&~3 -> prs row starts (4-edge aligned).
__global__ __launch_bounds__(1024) void scan1_kernel(const int* __restrict__ degd,
                                                     int* __restrict__ rs_all,
                                                     int* __restrict__ bsum) {
    int j = blockIdx.x, g = blockIdx.y;
    int i = j * 1024 + threadIdx.x;
    int v = (i < NN) ? ((degd[g * NN + i] + 3) & ~3) : 0;
    int lane = threadIdx.x & 63, w = threadIdx.x >> 6;
    int x = v;
    #pragma unroll
    for (int off = 1; off < 64; off <<= 1) {
        int t = __shfl_up(x, off, 64);
        if (lane >= off) x += t;
    }
    __shared__ int ws[17];
    if (lane == 63) ws[w] = x;
    __syncthreads();
    if (threadIdx.x == 0) {
        int run = 0;
        #pragma unroll
        for (int k = 0; k < 16; k++) { int t = ws[k]; ws[k] = run; run += t; }
        ws[16] = run;
    }
    __syncthreads();
    if (i < NN) rs_all[g * (NN + 1) + i] = ws[w] + x - v;
    if (threadIdx.x == 0) bsum[g * SCB + j] = ws[16];
}

__global__ void scan2_kernel(int* __restrict__ bsum, int* __restrict__ rs_all) {
    int g = threadIdx.x >> 6, lane = threadIdx.x & 63;
    int v = (lane < SCB) ? bsum[g * SCB + lane] : 0;
    int x = v;
    #pragma unroll
    for (int off = 1; off < 64; off <<= 1) {
        int t = __shfl_up(x, off, 64);
        if (lane >= off) x += t;
    }
    if (lane < SCB) bsum[g * SCB + lane] = x - v;   // exclusive
    if (lane == 63) rs_all[g * (NN + 1) + NN] = x;  // total padded edges
}

__global__ __launch_bounds__(1024) void scan3_kernel(const int* __restrict__ bsum,
                                                     int* __restrict__ rs_all) {
    int j = blockIdx.x, g = blockIdx.y;
    int i = j * 1024 + threadIdx.x;
    int off = bsum[g * SCB + j];
    if (i < NN) rs_all[g * (NN + 1) + i] += off;
}

// fill padded csr with the zero-row id NN (pad slots survive scatter).
__global__ __launch_bounds__(256) void cfill_kernel(uint* __restrict__ csr2) {
    int i = blockIdx.x * 256 + threadIdx.x;
    if (i < 4 * PEN / 2) csr2[i] = (uint)NN | ((uint)NN << 16);
}

__global__ __launch_bounds__(256) void scatter_kernel(GP src, GP dst,
                                                      const int* __restrict__ rs_all,
                                                      const uchar* __restrict__ pf,
                                                      ushort* __restrict__ csr) {
    int b = blockIdx.x, g = blockIdx.y;
    __shared__ uint lc[PBS / 4];
    for (int i = threadIdx.x; i < PBS / 4; i += 256) lc[i] = 0;
    __syncthreads();
    const int* sp = src.p[g];
    const int* dp = dst.p[g];
    const int* rs = rs_all + g * (NN + 1);
    const uchar* pfb = pf + (size_t)(g * NCH + b) * PBS;
    ushort* csrg = csr + (size_t)g * PEN;
    int e0 = b * CHE;
    for (int e = e0 + threadIdx.x; e < e0 + CHE; e += 256) {
        uint d = (uint)dp[e];
        int s = sp[e];
        uint sh = 8 * (d & 3);
        uint old = atomicAdd(&lc[d >> 2], 1u << sh);
        uint r = (old >> sh) & 0xFFu;
        csrg[rs[d] + (int)pfb[d] + (int)r] = (ushort)s;
    }
}

// ---- degree counting sort (chunked, atomic-free) -> perm -------------------

__global__ __launch_bounds__(256) void dhist_kernel(const int* __restrict__ degd,
                                                    int* __restrict__ dhp) {
    int b = blockIdx.x, g = blockIdx.y;
    __shared__ int lh[256];
    lh[threadIdx.x] = 0;
    __syncthreads();
    int n0 = b * DCN, nend = min(n0 + DCN, NN);
    for (int i = n0 + threadIdx.x; i < nend; i += 256) {
        int d = degd[g * NN + i];
        atomicAdd(&lh[d < 255 ? d : 255], 1);   // LDS only
    }
    __syncthreads();
    dhp[(g * DCH + b) * 256 + threadIdx.x] = lh[threadIdx.x];
}

__global__ void dscan_kernel(int* __restrict__ dhp, int* __restrict__ dbase) {
    int tid = threadIdx.x, lane = tid & 63, w = tid >> 6;
    __shared__ int ws[4];
    for (int g = 0; g < 4; g++) {
        int run = 0;
        for (int c = 0; c < DCH; c++) {
            int v = dhp[(g * DCH + c) * 256 + tid];
            dhp[(g * DCH + c) * 256 + tid] = run;
            run += v;
        }
        int x = run;
        #pragma unroll
        for (int off = 1; off < 64; off <<= 1) {
            int t = __shfl_up(x, off, 64);
            if (lane >= off) x += t;
        }
        if (lane == 63) ws[w] = x;
        __syncthreads();
        int prefix = 0;
        for (int j = 0; j < w; j++) prefix += ws[j];
        dbase[g * 256 + tid] = prefix + x - run;
        __syncthreads();
    }
}

__global__ __launch_bounds__(256) void dscatter_kernel(const int* __restrict__ degd,
                                                       const int* __restrict__ dhp,
                                                       const int* __restrict__ dbase,
                                                       int* __restrict__ perm) {
    int b = blockIdx.x, g = blockIdx.y;
    __shared__ int lc[256];
    lc[threadIdx.x] = 0;
    __syncthreads();
    int n0 = b * DCN, nend = min(n0 + DCN, NN);
    for (int i = n0 + threadIdx.x; i < nend; i += 256) {
        int d = degd[g * NN + i];
        d = d < 255 ? d : 255;
        int r = atomicAdd(&lc[d], 1);   // LDS only: within-chunk rank
        int pos = dbase[g * 256 + d] + dhp[(g * DCH + b) * 256 + d] + r;
        perm[g * NN + pos] = i;
    }
}

// ---- zero the pad rows (row NN) of xs (4 slices) and hbuf (8 slices) -------

__global__ void padzero_kernel(uint* __restrict__ xs, uint* __restrict__ hbuf) {
    int t = threadIdx.x;
    if (t < 32)  xs[(size_t)(t >> 3) * (NN + 1) * 8 + (size_t)NN * 8 + (t & 7)] = 0;
    if (t < 128) hbuf[(size_t)(t >> 4) * (NN + 1) * 16 + (size_t)NN * 16 + (t & 15)] = 0;
}

// ---- weight transpose/pad to bf16: Wt[n][k], stride WS = K+8 ---------------

__global__ __launch_bounds__(256) void wtrans_kernel(const float* __restrict__ W,
                                                     ushort* __restrict__ Wt,
                                                     int Kreal, int WS) {
    int idx = blockIdx.x * 256 + threadIdx.x;
    if (idx >= 320 * WS) return;
    int n = idx / WS, k = idx - n * WS;
    float v = (n < 304 && k < Kreal) ? W[k * 304 + n] : 0.f;
    Wt[idx] = f2bf(v);
}

// ---- prescale: xs = fp8(x * ns), sliced [4][(NN+1)][8 dwords] --------------

__global__ __launch_bounds__(256) void prescale_kernel(const float* __restrict__ x,
                                                       const float* __restrict__ ns,
                                                       uint* __restrict__ xs) {
    int idx = blockIdx.x * 256 + threadIdx.x;   // over NN*16 uint2 units
    if (idx >= NN * 16) return;
    int row = idx >> 4, j = idx & 15;
    int sl = j >> 2, pos = j & 3;
    float nv = ns[row];
    float4 v0 = ((const float4*)x)[idx * 2];
    float4 v1 = ((const float4*)x)[idx * 2 + 1];
    int p0 = 0, p1 = 0;
    p0 = __builtin_amdgcn_cvt_pk_fp8_f32(v0.x * nv, v0.y * nv, p0, false);
    p0 = __builtin_amdgcn_cvt_pk_fp8_f32(v0.z * nv, v0.w * nv, p0, true);
    p1 = __builtin_amdgcn_cvt_pk_fp8_f32(v1.x * nv, v1.y * nv, p1, false);
    p1 = __builtin_amdgcn_cvt_pk_fp8_f32(v1.z * nv, v1.w * nv, p1, true);
    ((uint2*)xs)[(size_t)sl * (NN + 1) * 4 + row * 4 + pos] = make_uint2((uint)p0, (uint)p1);
}

// ---- SpMM (sliced, group-owns-node, padded CSR, 1-line gathers) ------------

// xs: 4 slices x [(NN+1)][4 uint2] (32B rows). Wave = 16 groups x 4 lanes.
// m1 out: bf16 [NN][64 dw]. Grid (4, ceil(NN/64)).
__global__ __launch_bounds__(256) void spmm128_kernel(const uint2* __restrict__ xs,
                                                      const int* __restrict__ prs,
                                                      const ushort* __restrict__ csr,
                                                      const float* __restrict__ nd,
                                                      const int* __restrict__ perm,
                                                      uint4* __restrict__ out) {
    int wv = threadIdx.x >> 6, lane = threadIdx.x & 63;
    int grp = lane >> 2, gl = lane & 3;
    int slot = blockIdx.y * 64 + wv * 16 + grp;
    int sl = blockIdx.x;
    const uint2* base = xs + (size_t)sl * (NN + 1) * 4;
    bool ok = slot < NN;
    int node = ok ? perm[slot] : 0;
    int p0 = ok ? prs[node] : 0, p1 = ok ? prs[node + 1] : 0;
    float a[8] = {0.f, 0.f, 0.f, 0.f, 0.f, 0.f, 0.f, 0.f};
    float b[8] = {0.f, 0.f, 0.f, 0.f, 0.f, 0.f, 0.f, 0.f};
    for (int e = p0; e < p1; e += 4) {
        uint2 e4 = *(const uint2*)(csr + e);
        uint s0 = e4.x & 0xFFFFu, s1 = e4.x >> 16;
        uint s2 = e4.y & 0xFFFFu, s3 = e4.y >> 16;
        uint2 d0 = base[s0 * 4 + gl];
        uint2 d1 = base[s1 * 4 + gl];
        uint2 d2 = base[s2 * 4 + gl];
        uint2 d3 = base[s3 * 4 + gl];
        acc8(d0, a); acc8(d1, b); acc8(d2, a); acc8(d3, b);
    }
    if (ok) {
        float nv = nd[node];
        uint4 o;
        o.x = pk2((a[0] + b[0]) * nv, (a[1] + b[1]) * nv);
        o.y = pk2((a[2] + b[2]) * nv, (a[3] + b[3]) * nv);
        o.z = pk2((a[4] + b[4]) * nv, (a[5] + b[5]) * nv);
        o.w = pk2((a[6] + b[6]) * nv, (a[7] + b[7]) * nv);
        out[(size_t)node * 16 + sl * 4 + gl] = o;
    }
}

// hs: 8 slices x [(NN+1)][8 uint2] (64B rows, 40 fp8 used). Wave = 12 groups
// x 5 lanes (lanes 60-63 idle). mbuf out: bf16 [NN][160 dw]. Grid (8, ceil(NN/48)).
__global__ __launch_bounds__(256) void spmm320_kernel(const uint2* __restrict__ hs,
                                                      const int* __restrict__ prs,
                                                      const ushort* __restrict__ csr,
                                                      const float* __restrict__ nd,
                                                      const int* __restrict__ perm,
                                                      uint4* __restrict__ out) {
    int wv = threadIdx.x >> 6, lane = threadIdx.x & 63;
    int grp = lane / 5;              // 0..11 active, 12 idle
    int gl = lane - grp * 5;
    int slot = blockIdx.y * 48 + wv * 12 + grp;
    int sl = blockIdx.x;
    const uint2* base = hs + (size_t)sl * (NN + 1) * 8;
    bool ok = (grp < 12) && (slot < NN);
    int node = ok ? perm[slot] : 0;
    int p0 = ok ? prs[node] : 0, p1 = ok ? prs[node + 1] : 0;
    float a[8] = {0.f, 0.f, 0.f, 0.f, 0.f, 0.f, 0.f, 0.f};
    float b[8] = {0.f, 0.f, 0.f, 0.f, 0.f, 0.f, 0.f, 0.f};
    for (int e = p0; e < p1; e += 4) {
        uint2 e4 = *(const uint2*)(csr + e);
        uint s0 = e4.x & 0xFFFFu, s1 = e4.x >> 16;
        uint s2 = e4.y & 0xFFFFu, s3 = e4.y >> 16;
        uint2 d0 = base[s0 * 8 + gl];
        uint2 d1 = base[s1 * 8 + gl];
        uint2 d2 = base[s2 * 8 + gl];
        uint2 d3 = base[s3 * 8 + gl];
        acc8(d0, a); acc8(d1, b); acc8(d2, a); acc8(d3, b);
    }
    if (ok) {
        float nv = nd[node];
        uint4 o;
        o.x = pk2((a[0] + b[0]) * nv, (a[1] + b[1]) * nv);
        o.y = pk2((a[2] + b[2]) * nv, (a[3] + b[3]) * nv);
        o.z = pk2((a[4] + b[4]) * nv, (a[5] + b[5]) * nv);
        o.w = pk2((a[6] + b[6]) * nv, (a[7] + b[7]) * nv);
        out[(size_t)node * 40 + sl * 5 + gl] = o;
    }
}

// ---- GEMM: C[M x 320] = A[M x K] @ Wt^T, epilogue relu(+bias) --------------
// !REDUCE writes fp8 into 64B-stride slice layout. REDUCE sums into double.

template<int KSTEPS, bool REDUCE>
__global__ __launch_bounds__(256) void gemm_kernel(const ushort* __restrict__ A, int astride,
                                                   const ushort* __restrict__ Wt,
                                                   const float* __restrict__ bias,
                                                   const float* __restrict__ ns,
                                                   uchar* __restrict__ Hout,
                                                   double* __restrict__ accum,
                                                   int M) {
    constexpr int K = KSTEPS * 32;
    constexpr int WS = K + 8;   // pad: 2-way LDS conflicts only (free)
    __shared__ __align__(16) ushort wt[80 * WS];
    __shared__ float redbuf[4];
    int tid = threadIdx.x, lane = tid & 63, wv = tid >> 6;
    int nb = blockIdx.y * 80;
    int r0 = blockIdx.x * 128 + wv * 32;

    {   // stage 80 rows of Wt (16B vectors)
        const s8v* src = (const s8v*)(Wt + (size_t)nb * WS);
        s8v* dst = (s8v*)wt;
        for (int i = tid; i < 80 * WS / 8; i += 256) dst[i] = src[i];
    }
    __syncthreads();

    f4v acc[2][5];
    #pragma unroll
    for (int t = 0; t < 2; t++)
        #pragma unroll
        for (int j = 0; j < 5; j++) acc[t][j] = (f4v){0.f, 0.f, 0.f, 0.f};

    int m15 = lane & 15;
    int kq = (lane >> 4) * 8;
    int ar0 = min(r0 + m15, M - 1);
    int ar1 = min(r0 + 16 + m15, M - 1);
    const ushort* a0p = A + (size_t)ar0 * astride + kq;
    const ushort* a1p = A + (size_t)ar1 * astride + kq;
    const ushort* bb = wt + (size_t)m15 * WS + kq;

    #pragma unroll
    for (int ks = 0; ks < KSTEPS; ks++) {
        s8v af0 = *(const s8v*)(a0p + ks * 32);
        s8v af1 = *(const s8v*)(a1p + ks * 32);
        #pragma unroll
        for (int nt = 0; nt < 5; nt++) {
            s8v bf = *(const s8v*)(bb + nt * 16 * WS + ks * 32);
            acc[0][nt] = mfma16(af0, bf, acc[0][nt]);
            acc[1][nt] = mfma16(af1, bf, acc[1][nt]);
        }
    }

    int rq = (lane >> 4) * 4;   // C/D: col = lane&15, row = (lane>>4)*4 + reg
    if constexpr (!REDUCE) {
        float nsv[2][4];
        #pragma unroll
        for (int t = 0; t < 2; t++)
            #pragma unroll
            for (int r = 0; r < 4; r++) {
                int row = r0 + t * 16 + rq + r;
                nsv[t][r] = (row < M) ? ns[row] : 0.f;
            }
        #pragma unroll
        for (int nt = 0; nt < 5; nt++) {
            int col = nb + nt * 16 + m15;
            float bv = (col < 304) ? bias[col] : 0.f;
            int sl = col / 40, cw = col - sl * 40;
            uchar* hp = Hout + (size_t)sl * (NN + 1) * 64 + cw;
            #pragma unroll
            for (int t = 0; t < 2; t++)
                #pragma unroll
                for (int r = 0; r < 4; r++) {
                    int row = r0 + t * 16 + rq + r;
                    if (row < M) {
                        float y = fmaxf(acc[t][nt][r] + bv, 0.f) * nsv[t][r];
                        hp[(size_t)row * 64] = f2fp8(y);
                    }
                }
        }
    } else {
        float s = 0.f;
        #pragma unroll
        for (int nt = 0; nt < 5; nt++) {
            int col = nb + nt * 16 + m15;
            float bv = (col < 304) ? bias[col] : 0.f;
            #pragma unroll
            for (int t = 0; t < 2; t++)
                #pragma unroll
                for (int r = 0; r < 4; r++) {
                    int row = r0 + t * 16 + rq + r;
                    if (row < M && col < 304) s += fmaxf(acc[t][nt][r] + bv, 0.f);
                }
        }
        #pragma unroll
        for (int off = 32; off; off >>= 1) s += __shfl_xor(s, off, 64);
        if (lane == 0) redbuf[wv] = s;
        __syncthreads();
        if (tid == 0) {
            double b = (double)redbuf[0] + redbuf[1] + redbuf[2] + redbuf[3];
            atomicAdd(accum, b);
        }
    }
}

__global__ void finalize_kernel(const double* __restrict__ accum, float* __restrict__ out) {
    out[0] = (float)(accum[0] / (double)(4.0 * NN * 304.0));
}

// ---- host ------------------------------------------------------------------

extern "C" void kernel_launch(void* const* d_in, const int* in_sizes, int n_in,
                              void* d_out, int out_size, void* d_ws, size_t ws_size,
                              hipStream_t stream) {
    char* w = (char*)d_ws;
    auto alloc = [&](size_t bytes) {
        char* p = w;
        w += (bytes + 255) & ~(size_t)255;
        return p;
    };
    double* accum  = (double*)alloc(256);
    int*    degd   = (int*)alloc((size_t)4 * NN * 4);
    int*    rs     = (int*)alloc((size_t)4 * (NN + 1) * 4);   // padded row starts
    int*    bsum   = (int*)alloc((size_t)4 * SCB * 4);
    float*  nsrc   = (float*)alloc((size_t)4 * NN * 4);
    float*  ndst   = (float*)alloc((size_t)4 * NN * 4);
    ushort* csr    = (ushort*)alloc((size_t)4 * PEN * 2);     // u16, 4-edge padded
    int*    dhp    = (int*)alloc((size_t)4 * DCH * 256 * 4);
    int*    dbase  = (int*)alloc((size_t)4 * 256 * 4);
    int*    perm   = (int*)alloc((size_t)4 * NN * 4);
    ushort* wt1    = (ushort*)alloc((size_t)320 * 136 * 2);
    ushort* wt2    = (ushort*)alloc((size_t)320 * 328 * 2);
    ushort* wt3    = (ushort*)alloc((size_t)320 * 328 * 2);
    uint*   partS  = (uint*)alloc((size_t)4 * NCH * PBS);     // 12.8 MB
    uint*   partD  = (uint*)alloc((size_t)4 * NCH * PBS);     // 12.8 MB
    uint*   hbuf   = (uint*)alloc((size_t)8 * (NN + 1) * 64); // fp8 8-slice, 64B rows
    uint*   mbuf   = (uint*)alloc((size_t)NN * 160 * 4);      // bf16 N x 320
    // partS/partD dead after scatter: alias layer-1 buffers onto them.
    uint*   xs     = partS;   // fp8 4-slice (NN+1) x 32B: 6.4 MB <= 12.8 MB
    uint*   m1     = partD;   // bf16 N x 128: 12.8 MB <= 12.8 MB

    hipMemsetAsync(accum, 0, 256, stream);

    wtrans_kernel<<<(320 * 136 + 255) / 256, 256, 0, stream>>>((const float*)d_in[12], wt1, 128, 136);
    wtrans_kernel<<<(320 * 328 + 255) / 256, 256, 0, stream>>>((const float*)d_in[14], wt2, 304, 328);
    wtrans_kernel<<<(320 * 328 + 255) / 256, 256, 0, stream>>>((const float*)d_in[16], wt3, 304, 328);

    GP S, D;
    for (int g = 0; g < 4; g++) {
        S.p[g] = (const int*)d_in[1 + 3 * g];
        D.p[g] = (const int*)d_in[2 + 3 * g];
    }
    hist_kernel<<<dim3(NCH, 2, 4), 256, 0, stream>>>(S, D, partS, partD);
    reduce_kernel<<<(4 * NN + 255) / 256, 256, 0, stream>>>((const uchar*)partS, (uchar*)partD,
                                                            nsrc, ndst, degd);
    scan1_kernel<<<dim3(SCB, 4), 1024, 0, stream>>>(degd, rs, bsum);
    scan2_kernel<<<1, 256, 0, stream>>>(bsum, rs);
    scan3_kernel<<<dim3(SCB, 4), 1024, 0, stream>>>(bsum, rs);
    cfill_kernel<<<(4 * PEN / 2 + 255) / 256, 256, 0, stream>>>((uint*)csr);
    scatter_kernel<<<dim3(NCH, 4), 256, 0, stream>>>(S, D, rs, (const uchar*)partD, csr);
    dhist_kernel<<<dim3(DCH, 4), 256, 0, stream>>>(degd, dhp);
    dscan_kernel<<<1, 256, 0, stream>>>(dhp, dbase);
    dscatter_kernel<<<dim3(DCH, 4), 256, 0, stream>>>(degd, dhp, dbase, perm);
    padzero_kernel<<<1, 256, 0, stream>>>(xs, hbuf);

    const float* b1 = (const float*)d_in[13];
    const float* b2 = (const float*)d_in[15];
    const float* b3 = (const float*)d_in[17];
    dim3 ggrid((NN + 127) / 128, 4);

    for (int g = 0; g < 4; g++) {
        const float* xin = (const float*)d_in[3 * g];
        const float* nsg = nsrc + g * NN;
        const float* ndg = ndst + g * NN;
        const int* rsg = rs + g * (NN + 1);
        const ushort* csrg = csr + (size_t)g * PEN;
        const int* permg = perm + g * NN;

        prescale_kernel<<<(NN * 16 + 255) / 256, 256, 0, stream>>>(xin, nsg, xs);
        spmm128_kernel<<<dim3(4, (NN + 63) / 64), 256, 0, stream>>>((const uint2*)xs, rsg, csrg,
                                                                    ndg, permg, (uint4*)m1);
        gemm_kernel<4, false><<<ggrid, 256, 0, stream>>>((const ushort*)m1, 128, wt1, b1, nsg,
                                                         (uchar*)hbuf, nullptr, NN);
        spmm320_kernel<<<dim3(8, (NN + 47) / 48), 256, 0, stream>>>((const uint2*)hbuf, rsg, csrg,
                                                                    ndg, permg, (uint4*)mbuf);
        gemm_kernel<10, false><<<ggrid, 256, 0, stream>>>((const ushort*)mbuf, 320, wt2, b2, nsg,
                                                          (uchar*)hbuf, nullptr, NN);
        spmm320_kernel<<<dim3(8, (NN + 47) / 48), 256, 0, stream>>>((const uint2*)hbuf, rsg, csrg,
                                                                    ndg, permg, (uint4*)mbuf);
        gemm_kernel<10, true><<<ggrid, 256, 0, stream>>>((const ushort*)mbuf, 320, wt3, b3, nullptr,
                                                         nullptr, accum, NN);
    }
    finalize_kernel<<<1, 1, 0, stream>>>(accum, (float*)d_out);
}